// Round 1
// baseline (2715.086 us; speedup 1.0000x reference)
//
#include <hip/hip_runtime.h>

#define N_NODES 50000
#define N_EDGES 800000

__device__ __forceinline__ void fma4(float4& acc, float a, const float4& b) {
    acc.x = fmaf(a, b.x, acc.x);
    acc.y = fmaf(a, b.y, acc.y);
    acc.z = fmaf(a, b.z, acc.z);
    acc.w = fmaf(a, b.w, acc.w);
}

__device__ __forceinline__ float4 ld4(const float* p) {
    return *(const float4*)p;
}

// ---------------- degree ----------------
__global__ void deg_count_kernel(const int* __restrict__ dst, float* __restrict__ deg) {
    int i = blockIdx.x * blockDim.x + threadIdx.x;
    if (i < N_EDGES) atomicAdd(&deg[dst[i]], 1.0f);
}

__global__ void deg_inv_kernel(const float* __restrict__ deg, float* __restrict__ dinv) {
    int i = blockIdx.x * blockDim.x + threadIdx.x;
    if (i < N_NODES) {
        float d = deg[i];
        dinv[i] = d > 0.0f ? 1.0f / d : 0.0f;
    }
}

// ---------------- scatter-add (atomic) ----------------
template<int CH>
__global__ void scatter_add_kernel(const float* __restrict__ in, const int* __restrict__ src,
                                   const int* __restrict__ dst, float* __restrict__ out) {
    constexpr int TPE = CH / 4;
    long long tid = (long long)blockIdx.x * blockDim.x + threadIdx.x;
    int e = (int)(tid / TPE);
    int p = (int)(tid % TPE);
    if (e >= N_EDGES) return;
    int s = src[e], d = dst[e];
    float4 v = ld4(in + (size_t)s * CH + p * 4);
    float* o = out + (size_t)d * CH + p * 4;
    atomicAdd(o + 0, v.x);
    atomicAdd(o + 1, v.y);
    atomicAdd(o + 2, v.z);
    atomicAdd(o + 3, v.w);
}

// ---------------- layer 1 GEMM ----------------
// h1 = relu(dinv[n] * (acc1 @ W_rel) + x @ W_root + b1)
// acc1, x: [N_NODES, 64]; W: [64, 256]; h1: [N_NODES, 256]
__global__ __launch_bounds__(256) void gemm1_kernel(
    const float* __restrict__ acc1, const float* __restrict__ x, const float* __restrict__ dinv,
    const float* __restrict__ W_rel, const float* __restrict__ W_root,
    const float* __restrict__ b1, float* __restrict__ h1) {
    constexpr int K = 64, N = 256, KT = 16;
    __shared__ float Brel[KT * N];   // 16 KB
    __shared__ float Broot[KT * N];  // 16 KB
    const int tid = threadIdx.x;
    const int slot = tid >> 6;        // 0..3 (wave id, one row-slot per wave)
    const int col = (tid & 63) * 4;   // 0..252
    const int r0 = blockIdx.x * 8 + slot;  // 6250*8 = 50000 exact, no tail
    const int r1 = r0 + 4;
    float4 aR0 = {0,0,0,0}, aR1 = {0,0,0,0}, aT0 = {0,0,0,0}, aT1 = {0,0,0,0};
    for (int kt = 0; kt < K; kt += KT) {
        __syncthreads();
        for (int i = tid; i < KT * N / 4; i += 256) {
            ((float4*)Brel)[i]  = ((const float4*)(W_rel  + kt * N))[i];
            ((float4*)Broot)[i] = ((const float4*)(W_root + kt * N))[i];
        }
        __syncthreads();
        #pragma unroll
        for (int k = 0; k < KT; k += 4) {
            float ar0[4], ax0[4], ar1[4], ax1[4];
            *(float4*)ar0 = ld4(acc1 + r0 * K + kt + k);
            *(float4*)ax0 = ld4(x    + r0 * K + kt + k);
            *(float4*)ar1 = ld4(acc1 + r1 * K + kt + k);
            *(float4*)ax1 = ld4(x    + r1 * K + kt + k);
            #pragma unroll
            for (int kk = 0; kk < 4; ++kk) {
                float4 br = ld4(Brel  + (k + kk) * N + col);
                float4 bo = ld4(Broot + (k + kk) * N + col);
                fma4(aR0, ar0[kk], br);
                fma4(aR1, ar1[kk], br);
                fma4(aT0, ax0[kk], bo);
                fma4(aT1, ax1[kk], bo);
            }
        }
    }
    float d0 = dinv[r0], d1 = dinv[r1];
    float4 bb = ld4(b1 + col);
    float4 o0, o1;
    o0.x = fmaxf(fmaf(aR0.x, d0, aT0.x + bb.x), 0.0f);
    o0.y = fmaxf(fmaf(aR0.y, d0, aT0.y + bb.y), 0.0f);
    o0.z = fmaxf(fmaf(aR0.z, d0, aT0.z + bb.z), 0.0f);
    o0.w = fmaxf(fmaf(aR0.w, d0, aT0.w + bb.w), 0.0f);
    o1.x = fmaxf(fmaf(aR1.x, d1, aT1.x + bb.x), 0.0f);
    o1.y = fmaxf(fmaf(aR1.y, d1, aT1.y + bb.y), 0.0f);
    o1.z = fmaxf(fmaf(aR1.z, d1, aT1.z + bb.z), 0.0f);
    o1.w = fmaxf(fmaf(aR1.w, d1, aT1.w + bb.w), 0.0f);
    *(float4*)(h1 + (size_t)r0 * N + col) = o0;
    *(float4*)(h1 + (size_t)r1 * N + col) = o1;
}

// ---------------- layer 2 GEMM (rel part): t2 = h1 @ W2_rel ----------------
// h1: [N_NODES, 256]; W: [256, 128]; t2: [N_NODES, 128]
__global__ __launch_bounds__(256) void gemm2a_kernel(
    const float* __restrict__ h1, const float* __restrict__ W, float* __restrict__ t2) {
    constexpr int K = 256, N = 128, KT = 64;
    __shared__ float Bs[KT * N];  // 32 KB
    const int tid = threadIdx.x;
    const int slot = tid >> 5;        // 0..7
    const int col = (tid & 31) * 4;   // 0..124
    const int r0 = blockIdx.x * 16 + slot;  // 3125*16 = 50000 exact
    const int r1 = r0 + 8;
    float4 a0 = {0,0,0,0}, a1 = {0,0,0,0};
    for (int kt = 0; kt < K; kt += KT) {
        __syncthreads();
        for (int i = tid; i < KT * N / 4; i += 256)
            ((float4*)Bs)[i] = ((const float4*)(W + kt * N))[i];
        __syncthreads();
        #pragma unroll
        for (int k = 0; k < KT; k += 4) {
            float v0[4], v1[4];
            *(float4*)v0 = ld4(h1 + (size_t)r0 * K + kt + k);
            *(float4*)v1 = ld4(h1 + (size_t)r1 * K + kt + k);
            #pragma unroll
            for (int kk = 0; kk < 4; ++kk) {
                float4 b = ld4(Bs + (k + kk) * N + col);
                fma4(a0, v0[kk], b);
                fma4(a1, v1[kk], b);
            }
        }
    }
    *(float4*)(t2 + (size_t)r0 * N + col) = a0;
    *(float4*)(t2 + (size_t)r1 * N + col) = a1;
}

// ---------------- layer 2 GEMM (root) + combine: h2 = relu(a2*dinv + b2 + h1@W2_root) ----------------
__global__ __launch_bounds__(256) void gemm2b_kernel(
    const float* __restrict__ h1, const float* __restrict__ W,
    const float* __restrict__ a2, const float* __restrict__ dinv,
    const float* __restrict__ b2, float* __restrict__ h2) {
    constexpr int K = 256, N = 128, KT = 64;
    __shared__ float Bs[KT * N];
    const int tid = threadIdx.x;
    const int slot = tid >> 5;
    const int col = (tid & 31) * 4;
    const int r0 = blockIdx.x * 16 + slot;
    const int r1 = r0 + 8;
    float4 a0 = {0,0,0,0}, a1 = {0,0,0,0};
    for (int kt = 0; kt < K; kt += KT) {
        __syncthreads();
        for (int i = tid; i < KT * N / 4; i += 256)
            ((float4*)Bs)[i] = ((const float4*)(W + kt * N))[i];
        __syncthreads();
        #pragma unroll
        for (int k = 0; k < KT; k += 4) {
            float v0[4], v1[4];
            *(float4*)v0 = ld4(h1 + (size_t)r0 * K + kt + k);
            *(float4*)v1 = ld4(h1 + (size_t)r1 * K + kt + k);
            #pragma unroll
            for (int kk = 0; kk < 4; ++kk) {
                float4 b = ld4(Bs + (k + kk) * N + col);
                fma4(a0, v0[kk], b);
                fma4(a1, v1[kk], b);
            }
        }
    }
    float d0 = dinv[r0], d1 = dinv[r1];
    float4 bb = ld4(b2 + col);
    float4 g0 = ld4(a2 + (size_t)r0 * N + col);
    float4 g1 = ld4(a2 + (size_t)r1 * N + col);
    float4 o0, o1;
    o0.x = fmaxf(fmaf(g0.x, d0, a0.x + bb.x), 0.0f);
    o0.y = fmaxf(fmaf(g0.y, d0, a0.y + bb.y), 0.0f);
    o0.z = fmaxf(fmaf(g0.z, d0, a0.z + bb.z), 0.0f);
    o0.w = fmaxf(fmaf(g0.w, d0, a0.w + bb.w), 0.0f);
    o1.x = fmaxf(fmaf(g1.x, d1, a1.x + bb.x), 0.0f);
    o1.y = fmaxf(fmaf(g1.y, d1, a1.y + bb.y), 0.0f);
    o1.z = fmaxf(fmaf(g1.z, d1, a1.z + bb.z), 0.0f);
    o1.w = fmaxf(fmaf(g1.w, d1, a1.w + bb.w), 0.0f);
    *(float4*)(h2 + (size_t)r0 * N + col) = o0;
    *(float4*)(h2 + (size_t)r1 * N + col) = o1;
}

// ---------------- mu/ls GEMM (rel): tml = h2 @ [Wmu_rel | Wls_rel] ----------------
// h2: [N_NODES, 128]; each W: [128,16]; tml: [N_NODES, 32]
__global__ __launch_bounds__(256) void gemm3a_kernel(
    const float* __restrict__ h2, const float* __restrict__ Wmu, const float* __restrict__ Wls,
    float* __restrict__ tml) {
    constexpr int K = 128, N = 32;
    __shared__ float Bs[K * N];  // 16 KB
    const int tid = threadIdx.x;
    const int slot = tid >> 3;        // 0..31
    const int col = (tid & 7) * 4;    // 0..28
    int r0 = blockIdx.x * 64 + slot;
    int r1 = r0 + 32;
    const bool w0 = r0 < N_NODES, w1 = r1 < N_NODES;
    r0 = min(r0, N_NODES - 1);
    r1 = min(r1, N_NODES - 1);
    // stage: Bs[k*32 + j] = j<16 ? Wmu[k*16+j] : Wls[k*16+j-16]
    for (int i = tid; i < K * N / 4; i += 256) {
        int k = i >> 3, jq = i & 7;
        float4 v = (jq < 4) ? ((const float4*)Wmu)[k * 4 + jq]
                            : ((const float4*)Wls)[k * 4 + (jq - 4)];
        ((float4*)Bs)[i] = v;
    }
    __syncthreads();
    float4 a0 = {0,0,0,0}, a1 = {0,0,0,0};
    #pragma unroll 8
    for (int k = 0; k < K; k += 4) {
        float v0[4], v1[4];
        *(float4*)v0 = ld4(h2 + (size_t)r0 * K + k);
        *(float4*)v1 = ld4(h2 + (size_t)r1 * K + k);
        #pragma unroll
        for (int kk = 0; kk < 4; ++kk) {
            float4 b = ld4(Bs + (k + kk) * N + col);
            fma4(a0, v0[kk], b);
            fma4(a1, v1[kk], b);
        }
    }
    if (w0) *(float4*)(tml + (size_t)r0 * N + col) = a0;
    if (w1) *(float4*)(tml + (size_t)r1 * N + col) = a1;
}

// ---------------- mu/ls GEMM (root) + combine + split-write ----------------
// out_mu = aml[:, :16]*dinv + bmu + h2@Wmu_root ; out_ls likewise
__global__ __launch_bounds__(256) void gemm3b_kernel(
    const float* __restrict__ h2, const float* __restrict__ Wmu, const float* __restrict__ Wls,
    const float* __restrict__ aml, const float* __restrict__ dinv,
    const float* __restrict__ bmu, const float* __restrict__ bls,
    float* __restrict__ out) {
    constexpr int K = 128, N = 32;
    __shared__ float Bs[K * N];
    const int tid = threadIdx.x;
    const int slot = tid >> 3;
    const int col = (tid & 7) * 4;
    int r0 = blockIdx.x * 64 + slot;
    int r1 = r0 + 32;
    const bool w0 = r0 < N_NODES, w1 = r1 < N_NODES;
    r0 = min(r0, N_NODES - 1);
    r1 = min(r1, N_NODES - 1);
    for (int i = tid; i < K * N / 4; i += 256) {
        int k = i >> 3, jq = i & 7;
        float4 v = (jq < 4) ? ((const float4*)Wmu)[k * 4 + jq]
                            : ((const float4*)Wls)[k * 4 + (jq - 4)];
        ((float4*)Bs)[i] = v;
    }
    __syncthreads();
    float4 a0 = {0,0,0,0}, a1 = {0,0,0,0};
    #pragma unroll 8
    for (int k = 0; k < K; k += 4) {
        float v0[4], v1[4];
        *(float4*)v0 = ld4(h2 + (size_t)r0 * K + k);
        *(float4*)v1 = ld4(h2 + (size_t)r1 * K + k);
        #pragma unroll
        for (int kk = 0; kk < 4; ++kk) {
            float4 b = ld4(Bs + (k + kk) * N + col);
            fma4(a0, v0[kk], b);
            fma4(a1, v1[kk], b);
        }
    }
    float d0 = dinv[r0], d1 = dinv[r1];
    const float* bias = (col < 16) ? (bmu + col) : (bls + col - 16);
    float4 bb = ld4(bias);
    float4 g0 = ld4(aml + (size_t)r0 * N + col);
    float4 g1 = ld4(aml + (size_t)r1 * N + col);
    float4 o0, o1;
    o0.x = fmaf(g0.x, d0, a0.x + bb.x);
    o0.y = fmaf(g0.y, d0, a0.y + bb.y);
    o0.z = fmaf(g0.z, d0, a0.z + bb.z);
    o0.w = fmaf(g0.w, d0, a0.w + bb.w);
    o1.x = fmaf(g1.x, d1, a1.x + bb.x);
    o1.y = fmaf(g1.y, d1, a1.y + bb.y);
    o1.z = fmaf(g1.z, d1, a1.z + bb.z);
    o1.w = fmaf(g1.w, d1, a1.w + bb.w);
    // split: cols 0..15 -> mu (out[0 .. 800000)), cols 16..31 -> logstd
    size_t base0 = (col < 16) ? ((size_t)r0 * 16 + col) : (800000u + (size_t)r0 * 16 + col - 16);
    size_t base1 = (col < 16) ? ((size_t)r1 * 16 + col) : (800000u + (size_t)r1 * 16 + col - 16);
    if (w0) *(float4*)(out + base0) = o0;
    if (w1) *(float4*)(out + base1) = o1;
}

extern "C" void kernel_launch(void* const* d_in, const int* in_sizes, int n_in,
                              void* d_out, int out_size, void* d_ws, size_t ws_size,
                              hipStream_t stream) {
    const float* x       = (const float*)d_in[0];
    const float* W1_rel  = (const float*)d_in[1];
    const float* b1      = (const float*)d_in[2];
    const float* W1_root = (const float*)d_in[3];
    const float* W2_rel  = (const float*)d_in[4];
    const float* b2      = (const float*)d_in[5];
    const float* W2_root = (const float*)d_in[6];
    const float* Wmu_rel = (const float*)d_in[7];
    const float* bmu     = (const float*)d_in[8];
    const float* Wmu_root= (const float*)d_in[9];
    const float* Wls_rel = (const float*)d_in[10];
    const float* bls     = (const float*)d_in[11];
    const float* Wls_root= (const float*)d_in[12];
    const int*   ei      = (const int*)d_in[13];
    const int* src = ei;
    const int* dst = ei + N_EDGES;

    float* ws   = (float*)d_ws;
    float* deg  = ws;                    //   50,000
    float* dinv = ws + 50000;            //   50,000
    float* acc1 = ws + 100000;           // 3,200,000 (x-agg; later reused as tml)
    float* tml  = acc1;                  // 1,600,000 (after gemm1 consumes acc1)
    float* h1   = ws + 3300000;          // 12,800,000
    float* t2   = ws + 16100000;         // 6,400,000
    float* a2   = ws + 22500000;         // 6,400,000
    float* h2   = ws + 28900000;         // 6,400,000
    float* aml  = ws + 35300000;         // 1,600,000  (total 36.9M floats = 147.6 MB)
    float* out  = (float*)d_out;

    hipMemsetAsync(deg,  0,   50000 * sizeof(float), stream);
    hipMemsetAsync(acc1, 0, 3200000 * sizeof(float), stream);
    hipMemsetAsync(a2,   0, 6400000 * sizeof(float), stream);
    hipMemsetAsync(aml,  0, 1600000 * sizeof(float), stream);

    deg_count_kernel<<<(N_EDGES + 255) / 256, 256, 0, stream>>>(dst, deg);
    deg_inv_kernel<<<(N_NODES + 255) / 256, 256, 0, stream>>>(deg, dinv);

    // layer 1: aggregate x (64 ch), then fused double-GEMM + bias + relu
    scatter_add_kernel<64><<<(N_EDGES * 16 + 255) / 256, 256, 0, stream>>>(x, src, dst, acc1);
    gemm1_kernel<<<6250, 256, 0, stream>>>(acc1, x, dinv, W1_rel, W1_root, b1, h1);

    // layer 2: transform-first (128 ch), aggregate, combine with root GEMM
    gemm2a_kernel<<<3125, 256, 0, stream>>>(h1, W2_rel, t2);
    scatter_add_kernel<128><<<(N_EDGES * 32 + 255) / 256, 256, 0, stream>>>(t2, src, dst, a2);
    gemm2b_kernel<<<3125, 256, 0, stream>>>(h1, W2_root, a2, dinv, b2, h2);

    // mu/logstd: fused 128->32 transform, aggregate, combine + split write
    gemm3a_kernel<<<782, 256, 0, stream>>>(h2, Wmu_rel, Wls_rel, tml);
    scatter_add_kernel<32><<<(N_EDGES * 8 + 255) / 256, 256, 0, stream>>>(tml, src, dst, aml);
    gemm3b_kernel<<<782, 256, 0, stream>>>(h2, Wmu_root, Wls_root, aml, dinv, bmu, bls, out);
}

// Round 2
// 637.203 us; speedup vs baseline: 4.2609x; 4.2609x over previous
//
#include <hip/hip_runtime.h>

#define N_NODES 50000
#define N_EDGES 800000

__device__ __forceinline__ void fma4(float4& acc, float a, const float4& b) {
    acc.x = fmaf(a, b.x, acc.x);
    acc.y = fmaf(a, b.y, acc.y);
    acc.z = fmaf(a, b.z, acc.z);
    acc.w = fmaf(a, b.w, acc.w);
}

__device__ __forceinline__ float4 ld4(const float* p) {
    return *(const float4*)p;
}

// ---------------- CSR build ----------------
__global__ void hist_kernel(const int* __restrict__ dst, int* __restrict__ cnt) {
    int i = blockIdx.x * blockDim.x + threadIdx.x;
    if (i < N_EDGES) atomicAdd(&cnt[dst[i]], 1);
}

// single-block scan: row_ptr (exclusive), cursor copy, dinv = 1/deg
__global__ __launch_bounds__(1024) void scan_kernel(
    const int* __restrict__ cnt, int* __restrict__ row_ptr,
    int* __restrict__ cursor, float* __restrict__ dinv) {
    __shared__ int smem[1024];
    __shared__ int carry_s;
    const int tid = threadIdx.x;
    if (tid == 0) carry_s = 0;
    __syncthreads();
    for (int base = 0; base < N_NODES; base += 1024) {
        int i = base + tid;
        int orig = (i < N_NODES) ? cnt[i] : 0;
        smem[tid] = orig;
        __syncthreads();
        #pragma unroll
        for (int off = 1; off < 1024; off <<= 1) {
            int t = (tid >= off) ? smem[tid - off] : 0;
            __syncthreads();
            smem[tid] += t;
            __syncthreads();
        }
        int inc = smem[tid] + carry_s;
        int exc = inc - orig;
        if (i < N_NODES) {
            row_ptr[i] = exc;
            cursor[i] = exc;
            dinv[i] = orig > 0 ? 1.0f / (float)orig : 0.0f;
        }
        __syncthreads();
        if (tid == 1023) carry_s = inc;
        __syncthreads();
    }
    if (tid == 0) row_ptr[N_NODES] = N_EDGES;
}

__global__ void fill_kernel(const int* __restrict__ src, const int* __restrict__ dst,
                            int* __restrict__ cursor, int* __restrict__ eidx) {
    int e = blockIdx.x * blockDim.x + threadIdx.x;
    if (e < N_EDGES) {
        int slot = atomicAdd(&cursor[dst[e]], 1);
        eidx[slot] = src[e];
    }
}

// ---------------- gather-mean aggregation ----------------
// out[n, :] = dinv[n] * sum_{j in N(n)} in[eidx[j], :]
template<int CH>
__global__ __launch_bounds__(256) void gather_mean_kernel(
    const float* __restrict__ in, const int* __restrict__ row_ptr,
    const int* __restrict__ eidx, const float* __restrict__ dinv,
    float* __restrict__ out) {
    constexpr int LPN = CH / 4;        // lanes per node (float4 each)
    constexpr int NPB = 256 / LPN;     // nodes per block
    const int lane = threadIdx.x % LPN;
    const int nl = threadIdx.x / LPN;
    const int n = blockIdx.x * NPB + nl;
    if (n >= N_NODES) return;
    const int beg = row_ptr[n], end = row_ptr[n + 1];
    float4 a0 = {0,0,0,0}, a1 = {0,0,0,0};
    int j = beg;
    for (; j + 1 < end; j += 2) {
        int s0 = eidx[j], s1 = eidx[j + 1];
        float4 v0 = ld4(in + (size_t)s0 * CH + lane * 4);
        float4 v1 = ld4(in + (size_t)s1 * CH + lane * 4);
        a0.x += v0.x; a0.y += v0.y; a0.z += v0.z; a0.w += v0.w;
        a1.x += v1.x; a1.y += v1.y; a1.z += v1.z; a1.w += v1.w;
    }
    if (j < end) {
        int s0 = eidx[j];
        float4 v0 = ld4(in + (size_t)s0 * CH + lane * 4);
        a0.x += v0.x; a0.y += v0.y; a0.z += v0.z; a0.w += v0.w;
    }
    float d = dinv[n];
    float4 o;
    o.x = (a0.x + a1.x) * d;
    o.y = (a0.y + a1.y) * d;
    o.z = (a0.z + a1.z) * d;
    o.w = (a0.w + a1.w) * d;
    *(float4*)(out + (size_t)n * CH + lane * 4) = o;
}

// ---------------- layer 1 GEMM ----------------
// h1 = relu(agg1 @ W_rel + x @ W_root + b1)   (agg1 is already the mean)
__global__ __launch_bounds__(256) void gemm1_kernel(
    const float* __restrict__ agg1, const float* __restrict__ x,
    const float* __restrict__ W_rel, const float* __restrict__ W_root,
    const float* __restrict__ b1, float* __restrict__ h1) {
    constexpr int K = 64, N = 256, KT = 16;
    __shared__ float Brel[KT * N];   // 16 KB
    __shared__ float Broot[KT * N];  // 16 KB
    const int tid = threadIdx.x;
    const int slot = tid >> 6;
    const int col = (tid & 63) * 4;
    const int r0 = blockIdx.x * 8 + slot;  // 6250*8 = 50000 exact
    const int r1 = r0 + 4;
    float4 aR0 = {0,0,0,0}, aR1 = {0,0,0,0}, aT0 = {0,0,0,0}, aT1 = {0,0,0,0};
    for (int kt = 0; kt < K; kt += KT) {
        __syncthreads();
        for (int i = tid; i < KT * N / 4; i += 256) {
            ((float4*)Brel)[i]  = ((const float4*)(W_rel  + kt * N))[i];
            ((float4*)Broot)[i] = ((const float4*)(W_root + kt * N))[i];
        }
        __syncthreads();
        #pragma unroll
        for (int k = 0; k < KT; k += 4) {
            float ar0[4], ax0[4], ar1[4], ax1[4];
            *(float4*)ar0 = ld4(agg1 + r0 * K + kt + k);
            *(float4*)ax0 = ld4(x    + r0 * K + kt + k);
            *(float4*)ar1 = ld4(agg1 + r1 * K + kt + k);
            *(float4*)ax1 = ld4(x    + r1 * K + kt + k);
            #pragma unroll
            for (int kk = 0; kk < 4; ++kk) {
                float4 br = ld4(Brel  + (k + kk) * N + col);
                float4 bo = ld4(Broot + (k + kk) * N + col);
                fma4(aR0, ar0[kk], br);
                fma4(aR1, ar1[kk], br);
                fma4(aT0, ax0[kk], bo);
                fma4(aT1, ax1[kk], bo);
            }
        }
    }
    float4 bb = ld4(b1 + col);
    float4 o0, o1;
    o0.x = fmaxf(aR0.x + aT0.x + bb.x, 0.0f);
    o0.y = fmaxf(aR0.y + aT0.y + bb.y, 0.0f);
    o0.z = fmaxf(aR0.z + aT0.z + bb.z, 0.0f);
    o0.w = fmaxf(aR0.w + aT0.w + bb.w, 0.0f);
    o1.x = fmaxf(aR1.x + aT1.x + bb.x, 0.0f);
    o1.y = fmaxf(aR1.y + aT1.y + bb.y, 0.0f);
    o1.z = fmaxf(aR1.z + aT1.z + bb.z, 0.0f);
    o1.w = fmaxf(aR1.w + aT1.w + bb.w, 0.0f);
    *(float4*)(h1 + (size_t)r0 * N + col) = o0;
    *(float4*)(h1 + (size_t)r1 * N + col) = o1;
}

// ---------------- layer 2 GEMM (rel part): t2 = h1 @ W2_rel ----------------
__global__ __launch_bounds__(256) void gemm2a_kernel(
    const float* __restrict__ h1, const float* __restrict__ W, float* __restrict__ t2) {
    constexpr int K = 256, N = 128, KT = 64;
    __shared__ float Bs[KT * N];  // 32 KB
    const int tid = threadIdx.x;
    const int slot = tid >> 5;
    const int col = (tid & 31) * 4;
    const int r0 = blockIdx.x * 16 + slot;  // 3125*16 = 50000 exact
    const int r1 = r0 + 8;
    float4 a0 = {0,0,0,0}, a1 = {0,0,0,0};
    for (int kt = 0; kt < K; kt += KT) {
        __syncthreads();
        for (int i = tid; i < KT * N / 4; i += 256)
            ((float4*)Bs)[i] = ((const float4*)(W + kt * N))[i];
        __syncthreads();
        #pragma unroll
        for (int k = 0; k < KT; k += 4) {
            float v0[4], v1[4];
            *(float4*)v0 = ld4(h1 + (size_t)r0 * K + kt + k);
            *(float4*)v1 = ld4(h1 + (size_t)r1 * K + kt + k);
            #pragma unroll
            for (int kk = 0; kk < 4; ++kk) {
                float4 b = ld4(Bs + (k + kk) * N + col);
                fma4(a0, v0[kk], b);
                fma4(a1, v1[kk], b);
            }
        }
    }
    *(float4*)(t2 + (size_t)r0 * N + col) = a0;
    *(float4*)(t2 + (size_t)r1 * N + col) = a1;
}

// ---------------- layer 2 GEMM (root) + combine: h2 = relu(a2 + b2 + h1@W2_root) ----------------
__global__ __launch_bounds__(256) void gemm2b_kernel(
    const float* __restrict__ h1, const float* __restrict__ W,
    const float* __restrict__ a2, const float* __restrict__ b2, float* __restrict__ h2) {
    constexpr int K = 256, N = 128, KT = 64;
    __shared__ float Bs[KT * N];
    const int tid = threadIdx.x;
    const int slot = tid >> 5;
    const int col = (tid & 31) * 4;
    const int r0 = blockIdx.x * 16 + slot;
    const int r1 = r0 + 8;
    float4 a0 = {0,0,0,0}, a1 = {0,0,0,0};
    for (int kt = 0; kt < K; kt += KT) {
        __syncthreads();
        for (int i = tid; i < KT * N / 4; i += 256)
            ((float4*)Bs)[i] = ((const float4*)(W + kt * N))[i];
        __syncthreads();
        #pragma unroll
        for (int k = 0; k < KT; k += 4) {
            float v0[4], v1[4];
            *(float4*)v0 = ld4(h1 + (size_t)r0 * K + kt + k);
            *(float4*)v1 = ld4(h1 + (size_t)r1 * K + kt + k);
            #pragma unroll
            for (int kk = 0; kk < 4; ++kk) {
                float4 b = ld4(Bs + (k + kk) * N + col);
                fma4(a0, v0[kk], b);
                fma4(a1, v1[kk], b);
            }
        }
    }
    float4 bb = ld4(b2 + col);
    float4 g0 = ld4(a2 + (size_t)r0 * N + col);
    float4 g1 = ld4(a2 + (size_t)r1 * N + col);
    float4 o0, o1;
    o0.x = fmaxf(g0.x + a0.x + bb.x, 0.0f);
    o0.y = fmaxf(g0.y + a0.y + bb.y, 0.0f);
    o0.z = fmaxf(g0.z + a0.z + bb.z, 0.0f);
    o0.w = fmaxf(g0.w + a0.w + bb.w, 0.0f);
    o1.x = fmaxf(g1.x + a1.x + bb.x, 0.0f);
    o1.y = fmaxf(g1.y + a1.y + bb.y, 0.0f);
    o1.z = fmaxf(g1.z + a1.z + bb.z, 0.0f);
    o1.w = fmaxf(g1.w + a1.w + bb.w, 0.0f);
    *(float4*)(h2 + (size_t)r0 * N + col) = o0;
    *(float4*)(h2 + (size_t)r1 * N + col) = o1;
}

// ---------------- mu/ls GEMM (rel): tml = h2 @ [Wmu_rel | Wls_rel] ----------------
__global__ __launch_bounds__(256) void gemm3a_kernel(
    const float* __restrict__ h2, const float* __restrict__ Wmu, const float* __restrict__ Wls,
    float* __restrict__ tml) {
    constexpr int K = 128, N = 32;
    __shared__ float Bs[K * N];  // 16 KB
    const int tid = threadIdx.x;
    const int slot = tid >> 3;
    const int col = (tid & 7) * 4;
    int r0 = blockIdx.x * 64 + slot;
    int r1 = r0 + 32;
    const bool w0 = r0 < N_NODES, w1 = r1 < N_NODES;
    r0 = min(r0, N_NODES - 1);
    r1 = min(r1, N_NODES - 1);
    for (int i = tid; i < K * N / 4; i += 256) {
        int k = i >> 3, jq = i & 7;
        float4 v = (jq < 4) ? ((const float4*)Wmu)[k * 4 + jq]
                            : ((const float4*)Wls)[k * 4 + (jq - 4)];
        ((float4*)Bs)[i] = v;
    }
    __syncthreads();
    float4 a0 = {0,0,0,0}, a1 = {0,0,0,0};
    #pragma unroll 8
    for (int k = 0; k < K; k += 4) {
        float v0[4], v1[4];
        *(float4*)v0 = ld4(h2 + (size_t)r0 * K + k);
        *(float4*)v1 = ld4(h2 + (size_t)r1 * K + k);
        #pragma unroll
        for (int kk = 0; kk < 4; ++kk) {
            float4 b = ld4(Bs + (k + kk) * N + col);
            fma4(a0, v0[kk], b);
            fma4(a1, v1[kk], b);
        }
    }
    if (w0) *(float4*)(tml + (size_t)r0 * N + col) = a0;
    if (w1) *(float4*)(tml + (size_t)r1 * N + col) = a1;
}

// ---------------- mu/ls GEMM (root) + combine + split-write ----------------
__global__ __launch_bounds__(256) void gemm3b_kernel(
    const float* __restrict__ h2, const float* __restrict__ Wmu, const float* __restrict__ Wls,
    const float* __restrict__ aml,
    const float* __restrict__ bmu, const float* __restrict__ bls,
    float* __restrict__ out) {
    constexpr int K = 128, N = 32;
    __shared__ float Bs[K * N];
    const int tid = threadIdx.x;
    const int slot = tid >> 3;
    const int col = (tid & 7) * 4;
    int r0 = blockIdx.x * 64 + slot;
    int r1 = r0 + 32;
    const bool w0 = r0 < N_NODES, w1 = r1 < N_NODES;
    r0 = min(r0, N_NODES - 1);
    r1 = min(r1, N_NODES - 1);
    for (int i = tid; i < K * N / 4; i += 256) {
        int k = i >> 3, jq = i & 7;
        float4 v = (jq < 4) ? ((const float4*)Wmu)[k * 4 + jq]
                            : ((const float4*)Wls)[k * 4 + (jq - 4)];
        ((float4*)Bs)[i] = v;
    }
    __syncthreads();
    float4 a0 = {0,0,0,0}, a1 = {0,0,0,0};
    #pragma unroll 8
    for (int k = 0; k < K; k += 4) {
        float v0[4], v1[4];
        *(float4*)v0 = ld4(h2 + (size_t)r0 * K + k);
        *(float4*)v1 = ld4(h2 + (size_t)r1 * K + k);
        #pragma unroll
        for (int kk = 0; kk < 4; ++kk) {
            float4 b = ld4(Bs + (k + kk) * N + col);
            fma4(a0, v0[kk], b);
            fma4(a1, v1[kk], b);
        }
    }
    const float* bias = (col < 16) ? (bmu + col) : (bls + col - 16);
    float4 bb = ld4(bias);
    float4 g0 = ld4(aml + (size_t)r0 * N + col);
    float4 g1 = ld4(aml + (size_t)r1 * N + col);
    float4 o0, o1;
    o0.x = g0.x + a0.x + bb.x;
    o0.y = g0.y + a0.y + bb.y;
    o0.z = g0.z + a0.z + bb.z;
    o0.w = g0.w + a0.w + bb.w;
    o1.x = g1.x + a1.x + bb.x;
    o1.y = g1.y + a1.y + bb.y;
    o1.z = g1.z + a1.z + bb.z;
    o1.w = g1.w + a1.w + bb.w;
    size_t base0 = (col < 16) ? ((size_t)r0 * 16 + col) : (800000u + (size_t)r0 * 16 + col - 16);
    size_t base1 = (col < 16) ? ((size_t)r1 * 16 + col) : (800000u + (size_t)r1 * 16 + col - 16);
    if (w0) *(float4*)(out + base0) = o0;
    if (w1) *(float4*)(out + base1) = o1;
}

extern "C" void kernel_launch(void* const* d_in, const int* in_sizes, int n_in,
                              void* d_out, int out_size, void* d_ws, size_t ws_size,
                              hipStream_t stream) {
    const float* x       = (const float*)d_in[0];
    const float* W1_rel  = (const float*)d_in[1];
    const float* b1      = (const float*)d_in[2];
    const float* W1_root = (const float*)d_in[3];
    const float* W2_rel  = (const float*)d_in[4];
    const float* b2      = (const float*)d_in[5];
    const float* W2_root = (const float*)d_in[6];
    const float* Wmu_rel = (const float*)d_in[7];
    const float* bmu     = (const float*)d_in[8];
    const float* Wmu_root= (const float*)d_in[9];
    const float* Wls_rel = (const float*)d_in[10];
    const float* bls     = (const float*)d_in[11];
    const float* Wls_root= (const float*)d_in[12];
    const int*   ei      = (const int*)d_in[13];
    const int* src = ei;
    const int* dst = ei + N_EDGES;

    // ---- workspace layout ----
    int*   cnt     = (int*)d_ws;           // 50,000
    int*   row_ptr = cnt + 50000;          // 50,001
    int*   cursor  = row_ptr + 50001;      // 50,000
    int*   eidx    = cursor + 50000;       // 800,000   (950,051 ints)
    float* fbase   = (float*)d_ws + 950052;
    float* dinv    = fbase;                //    50,000
    float* agg1    = fbase + 50000;        // 3,200,000 (reused as tml later)
    float* tml     = agg1;
    float* h1      = agg1 + 3200000;       // 12,800,000
    float* t2      = h1 + 12800000;        // 6,400,000 (reused as aml later)
    float* aml     = t2;
    float* a2      = t2 + 6400000;         // 6,400,000
    float* h2      = a2 + 6400000;         // 6,400,000  (total ~36.2M elems ~145 MB)
    float* out     = (float*)d_out;

    // ---- CSR build ----
    hipMemsetAsync(cnt, 0, 50000 * sizeof(int), stream);
    hist_kernel<<<3125, 256, 0, stream>>>(dst, cnt);
    scan_kernel<<<1, 1024, 0, stream>>>(cnt, row_ptr, cursor, dinv);
    fill_kernel<<<3125, 256, 0, stream>>>(src, dst, cursor, eidx);

    // ---- layer 1: aggregate x (64 ch), fused double-GEMM + bias + relu ----
    gather_mean_kernel<64><<<3125, 256, 0, stream>>>(x, row_ptr, eidx, dinv, agg1);
    gemm1_kernel<<<6250, 256, 0, stream>>>(agg1, x, W1_rel, W1_root, b1, h1);

    // ---- layer 2: transform-first (128 ch), aggregate, combine ----
    gemm2a_kernel<<<3125, 256, 0, stream>>>(h1, W2_rel, t2);
    gather_mean_kernel<128><<<6250, 256, 0, stream>>>(t2, row_ptr, eidx, dinv, a2);
    gemm2b_kernel<<<3125, 256, 0, stream>>>(h1, W2_root, a2, b2, h2);

    // ---- mu/logstd: fused 128->32 transform, aggregate, combine + split ----
    gemm3a_kernel<<<782, 256, 0, stream>>>(h2, Wmu_rel, Wls_rel, tml);
    gather_mean_kernel<32><<<1563, 256, 0, stream>>>(tml, row_ptr, eidx, dinv, aml);
    gemm3b_kernel<<<782, 256, 0, stream>>>(h2, Wmu_root, Wls_root, aml, bmu, bls, out);
}

// Round 3
// 416.004 us; speedup vs baseline: 6.5266x; 1.5317x over previous
//
#include <hip/hip_runtime.h>

#define N_NODES 50000
#define N_EDGES 800000

typedef unsigned short ushort_t;
typedef short short8 __attribute__((ext_vector_type(8)));
typedef float floatx4 __attribute__((ext_vector_type(4)));

__device__ __forceinline__ float bf2f(ushort_t u) {
    unsigned v = ((unsigned)u) << 16;
    return __builtin_bit_cast(float, v);
}
__device__ __forceinline__ ushort_t f2bf(float f) {
    unsigned u = __builtin_bit_cast(unsigned, f);
    unsigned r = (u + 0x7FFFu + ((u >> 16) & 1u)) >> 16;  // RNE
    return (ushort_t)r;
}
__device__ __forceinline__ float4 ld4(const float* p) { return *(const float4*)p; }

// ---------------- CSR build ----------------
__global__ void hist_kernel(const int* __restrict__ dst, int* __restrict__ cnt) {
    int i = blockIdx.x * blockDim.x + threadIdx.x;
    if (i < N_EDGES) atomicAdd(&cnt[dst[i]], 1);
}

__global__ __launch_bounds__(1024) void scan_kernel(
    const int* __restrict__ cnt, int* __restrict__ row_ptr,
    int* __restrict__ cursor, float* __restrict__ dinv) {
    __shared__ int smem[1024];
    __shared__ int carry_s;
    const int tid = threadIdx.x;
    if (tid == 0) carry_s = 0;
    __syncthreads();
    for (int base = 0; base < N_NODES; base += 1024) {
        int i = base + tid;
        int orig = (i < N_NODES) ? cnt[i] : 0;
        smem[tid] = orig;
        __syncthreads();
        #pragma unroll
        for (int off = 1; off < 1024; off <<= 1) {
            int t = (tid >= off) ? smem[tid - off] : 0;
            __syncthreads();
            smem[tid] += t;
            __syncthreads();
        }
        int inc = smem[tid] + carry_s;
        int exc = inc - orig;
        if (i < N_NODES) {
            row_ptr[i] = exc;
            cursor[i] = exc;
            dinv[i] = orig > 0 ? 1.0f / (float)orig : 0.0f;
        }
        __syncthreads();
        if (tid == 1023) carry_s = inc;
        __syncthreads();
    }
    if (tid == 0) row_ptr[N_NODES] = N_EDGES;
}

__global__ void fill_kernel(const int* __restrict__ src, const int* __restrict__ dst,
                            int* __restrict__ cursor, int* __restrict__ eidx) {
    int e = blockIdx.x * blockDim.x + threadIdx.x;
    if (e < N_EDGES) {
        int slot = atomicAdd(&cursor[dst[e]], 1);
        eidx[slot] = src[e];
    }
}

// ---------------- conversions ----------------
// ax[n, 64:128] = bf16(x[n, :])   (ax is [N_NODES, 128] bf16)
__global__ __launch_bounds__(256) void cvt_x_kernel(const float* __restrict__ x,
                                                    ushort_t* __restrict__ ax) {
    int idx = blockIdx.x * blockDim.x + threadIdx.x;
    if (idx >= N_NODES * 8) return;
    int n = idx >> 3, c = (idx & 7) * 8;
    float4 v0 = ld4(x + (size_t)n * 64 + c);
    float4 v1 = ld4(x + (size_t)n * 64 + c + 4);
    short8 o;
    o[0] = f2bf(v0.x); o[1] = f2bf(v0.y); o[2] = f2bf(v0.z); o[3] = f2bf(v0.w);
    o[4] = f2bf(v1.x); o[5] = f2bf(v1.y); o[6] = f2bf(v1.z); o[7] = f2bf(v1.w);
    *(short8*)(ax + (size_t)n * 128 + 64 + c) = o;
}

// Build transposed bf16 weight mats:
// B1t[256 n][128 k]: k<64 -> W1_rel[k][n], else W1_root[k-64][n]
// B2t[256 n][256 k]: n<128 -> W2_rel[k][n], else W2_root[k][n-128]
// B3t[64 n][128 k]:  n>>4 selects {Wmu_rel, Wls_rel, Wmu_root, Wls_root}[k][n&15]
__global__ __launch_bounds__(256) void cvt_w_kernel(
    const float* __restrict__ W1_rel, const float* __restrict__ W1_root,
    const float* __restrict__ W2_rel, const float* __restrict__ W2_root,
    const float* __restrict__ Wmu_rel, const float* __restrict__ Wls_rel,
    const float* __restrict__ Wmu_root, const float* __restrict__ Wls_root,
    ushort_t* __restrict__ B1t, ushort_t* __restrict__ B2t, ushort_t* __restrict__ B3t) {
    int idx = blockIdx.x * blockDim.x + threadIdx.x;
    if (idx < 32768) {
        int n = idx >> 7, k = idx & 127;
        float v = (k < 64) ? W1_rel[k * 256 + n] : W1_root[(k - 64) * 256 + n];
        B1t[idx] = f2bf(v);
    } else if (idx < 98304) {
        int j = idx - 32768;
        int n = j >> 8, k = j & 255;
        float v = (n < 128) ? W2_rel[k * 128 + n] : W2_root[k * 128 + (n - 128)];
        B2t[j] = f2bf(v);
    } else if (idx < 106496) {
        int j = idx - 98304;
        int n = j >> 7, k = j & 127;
        const float* W = (n < 16) ? Wmu_rel : (n < 32) ? Wls_rel : (n < 48) ? Wmu_root : Wls_root;
        B3t[j] = f2bf(W[k * 16 + (n & 15)]);
    }
}

// ---------------- gather 1: ax[:, 0:64] = mean-gather of ax[:, 64:128] ----------------
__global__ __launch_bounds__(256) void gather1_kernel(
    const int* __restrict__ row_ptr, const int* __restrict__ eidx,
    const float* __restrict__ dinv, ushort_t* __restrict__ ax) {
    const int lane = threadIdx.x & 7;        // 8 lanes/node, 8 ch each
    const int nl = threadIdx.x >> 3;
    const int n = blockIdx.x * 32 + nl;
    if (n >= N_NODES) return;
    const int beg = row_ptr[n], end = row_ptr[n + 1];
    float a0[8] = {0,0,0,0,0,0,0,0}, a1[8] = {0,0,0,0,0,0,0,0};
    int j = beg;
    for (; j + 1 < end; j += 2) {
        int s0 = eidx[j], s1 = eidx[j + 1];
        short8 v0 = *(const short8*)(ax + (size_t)s0 * 128 + 64 + lane * 8);
        short8 v1 = *(const short8*)(ax + (size_t)s1 * 128 + 64 + lane * 8);
        #pragma unroll
        for (int i = 0; i < 8; ++i) { a0[i] += bf2f((ushort_t)v0[i]); a1[i] += bf2f((ushort_t)v1[i]); }
    }
    if (j < end) {
        int s0 = eidx[j];
        short8 v0 = *(const short8*)(ax + (size_t)s0 * 128 + 64 + lane * 8);
        #pragma unroll
        for (int i = 0; i < 8; ++i) a0[i] += bf2f((ushort_t)v0[i]);
    }
    float d = dinv[n];
    short8 o;
    #pragma unroll
    for (int i = 0; i < 8; ++i) o[i] = f2bf((a0[i] + a1[i]) * d);
    *(short8*)(ax + (size_t)n * 128 + lane * 8) = o;
}

// ---------------- MFMA GEMMs ----------------
// Each block: 4 waves x 16 rows = 64 rows of M; one 64-col N-tile (blockIdx.y).
// A frag: lane holds A[m=lane&15][k=quad*8+j]; B frag from Bt LDS (row=n, contiguous k);
// C/D: col=lane&15, row=quad*4+reg.

// gemm1: h1 = relu(ax @ [W1_rel;W1_root] + b1), A=[50000,128] bf16, N=256
__global__ __launch_bounds__(256) void gemm1_mfma(
    const ushort_t* __restrict__ A, const ushort_t* __restrict__ Bt,
    const float* __restrict__ b1, ushort_t* __restrict__ h1) {
    constexpr int K = 128, KP = K + 8;
    __shared__ ushort_t Bs[64 * KP];
    const int tid = threadIdx.x;
    const int w = tid >> 6, lane = tid & 63;
    const int ln = lane & 15, quad = lane >> 4;
    const int ny = blockIdx.y;
    const int rowbase = blockIdx.x * 64 + w * 16;
    for (int i = tid; i < 64 * K / 8; i += 256) {
        int row = i / (K / 8), off = i % (K / 8);
        *(short8*)(Bs + row * KP + off * 8) = *(const short8*)(Bt + (size_t)(ny * 64 + row) * K + off * 8);
    }
    __syncthreads();
    int r = rowbase + ln; if (r > N_NODES - 1) r = N_NODES - 1;
    short8 a[4];
    #pragma unroll
    for (int s = 0; s < 4; ++s)
        a[s] = *(const short8*)(A + (size_t)r * K + s * 32 + quad * 8);
    floatx4 acc[4] = {};
    #pragma unroll
    for (int f = 0; f < 4; ++f) {
        const ushort_t* bp = Bs + (f * 16 + ln) * KP + quad * 8;
        #pragma unroll
        for (int s = 0; s < 4; ++s) {
            short8 b = *(const short8*)(bp + s * 32);
            acc[f] = __builtin_amdgcn_mfma_f32_16x16x32_bf16(a[s], b, acc[f], 0, 0, 0);
        }
    }
    const int r0 = rowbase + quad * 4;
    #pragma unroll
    for (int f = 0; f < 4; ++f) {
        int n = ny * 64 + f * 16 + ln;
        float bias = b1[n];
        #pragma unroll
        for (int g = 0; g < 4; ++g) {
            int rr = r0 + g;
            if (rr >= N_NODES) continue;
            h1[(size_t)rr * 256 + n] = f2bf(fmaxf(acc[f][g] + bias, 0.0f));
        }
    }
}

// gemm2: [t2 | r2] = h1 @ [W2_rel | W2_root]; t2 bf16 (cols 0-127), r2 fp32 (cols 128-255)
__global__ __launch_bounds__(256) void gemm2_mfma(
    const ushort_t* __restrict__ A, const ushort_t* __restrict__ Bt,
    ushort_t* __restrict__ t2, float* __restrict__ r2) {
    constexpr int K = 256, KP = K + 8;
    __shared__ ushort_t Bs[64 * KP];
    const int tid = threadIdx.x;
    const int w = tid >> 6, lane = tid & 63;
    const int ln = lane & 15, quad = lane >> 4;
    const int ny = blockIdx.y;
    const int rowbase = blockIdx.x * 64 + w * 16;
    for (int i = tid; i < 64 * K / 8; i += 256) {
        int row = i / (K / 8), off = i % (K / 8);
        *(short8*)(Bs + row * KP + off * 8) = *(const short8*)(Bt + (size_t)(ny * 64 + row) * K + off * 8);
    }
    __syncthreads();
    int r = rowbase + ln; if (r > N_NODES - 1) r = N_NODES - 1;
    short8 a[8];
    #pragma unroll
    for (int s = 0; s < 8; ++s)
        a[s] = *(const short8*)(A + (size_t)r * K + s * 32 + quad * 8);
    floatx4 acc[4] = {};
    #pragma unroll
    for (int f = 0; f < 4; ++f) {
        const ushort_t* bp = Bs + (f * 16 + ln) * KP + quad * 8;
        #pragma unroll
        for (int s = 0; s < 8; ++s) {
            short8 b = *(const short8*)(bp + s * 32);
            acc[f] = __builtin_amdgcn_mfma_f32_16x16x32_bf16(a[s], b, acc[f], 0, 0, 0);
        }
    }
    const int r0 = rowbase + quad * 4;
    #pragma unroll
    for (int f = 0; f < 4; ++f) {
        int n = ny * 64 + f * 16 + ln;
        #pragma unroll
        for (int g = 0; g < 4; ++g) {
            int rr = r0 + g;
            if (rr >= N_NODES) continue;
            float v = acc[f][g];
            if (n < 128) t2[(size_t)rr * 128 + n] = f2bf(v);
            else r2[(size_t)rr * 128 + (n - 128)] = v;
        }
    }
}

// gemm3: [tml | rml] = h2 @ [Wmu_rel|Wls_rel|Wmu_root|Wls_root]; tml bf16 (0-31), rml fp32 (32-63)
__global__ __launch_bounds__(256) void gemm3_mfma(
    const ushort_t* __restrict__ A, const ushort_t* __restrict__ Bt,
    ushort_t* __restrict__ tml, float* __restrict__ rml) {
    constexpr int K = 128, KP = K + 8;
    __shared__ ushort_t Bs[64 * KP];
    const int tid = threadIdx.x;
    const int w = tid >> 6, lane = tid & 63;
    const int ln = lane & 15, quad = lane >> 4;
    const int rowbase = blockIdx.x * 64 + w * 16;
    for (int i = tid; i < 64 * K / 8; i += 256) {
        int row = i / (K / 8), off = i % (K / 8);
        *(short8*)(Bs + row * KP + off * 8) = *(const short8*)(Bt + (size_t)row * K + off * 8);
    }
    __syncthreads();
    int r = rowbase + ln; if (r > N_NODES - 1) r = N_NODES - 1;
    short8 a[4];
    #pragma unroll
    for (int s = 0; s < 4; ++s)
        a[s] = *(const short8*)(A + (size_t)r * K + s * 32 + quad * 8);
    floatx4 acc[4] = {};
    #pragma unroll
    for (int f = 0; f < 4; ++f) {
        const ushort_t* bp = Bs + (f * 16 + ln) * KP + quad * 8;
        #pragma unroll
        for (int s = 0; s < 4; ++s) {
            short8 b = *(const short8*)(bp + s * 32);
            acc[f] = __builtin_amdgcn_mfma_f32_16x16x32_bf16(a[s], b, acc[f], 0, 0, 0);
        }
    }
    const int r0 = rowbase + quad * 4;
    #pragma unroll
    for (int f = 0; f < 4; ++f) {
        int n = f * 16 + ln;
        #pragma unroll
        for (int g = 0; g < 4; ++g) {
            int rr = r0 + g;
            if (rr >= N_NODES) continue;
            float v = acc[f][g];
            if (n < 32) tml[(size_t)rr * 32 + n] = f2bf(v);
            else rml[(size_t)rr * 32 + (n - 32)] = v;
        }
    }
}

// ---------------- gather 2 (fused combine): h2 = relu(mean-gather(t2) + r2 + b2), bf16 out ----------------
__global__ __launch_bounds__(256) void gather2_kernel(
    const ushort_t* __restrict__ t2, const float* __restrict__ r2,
    const int* __restrict__ row_ptr, const int* __restrict__ eidx,
    const float* __restrict__ dinv, const float* __restrict__ b2,
    ushort_t* __restrict__ h2) {
    const int lane = threadIdx.x & 15;       // 16 lanes/node, 8 ch each
    const int nl = threadIdx.x >> 4;
    const int n = blockIdx.x * 16 + nl;      // 3125*16 = 50000 exact
    const int beg = row_ptr[n], end = row_ptr[n + 1];
    float a0[8] = {0,0,0,0,0,0,0,0}, a1[8] = {0,0,0,0,0,0,0,0};
    int j = beg;
    for (; j + 1 < end; j += 2) {
        int s0 = eidx[j], s1 = eidx[j + 1];
        short8 v0 = *(const short8*)(t2 + (size_t)s0 * 128 + lane * 8);
        short8 v1 = *(const short8*)(t2 + (size_t)s1 * 128 + lane * 8);
        #pragma unroll
        for (int i = 0; i < 8; ++i) { a0[i] += bf2f((ushort_t)v0[i]); a1[i] += bf2f((ushort_t)v1[i]); }
    }
    if (j < end) {
        int s0 = eidx[j];
        short8 v0 = *(const short8*)(t2 + (size_t)s0 * 128 + lane * 8);
        #pragma unroll
        for (int i = 0; i < 8; ++i) a0[i] += bf2f((ushort_t)v0[i]);
    }
    float d = dinv[n];
    float4 ra = ld4(r2 + (size_t)n * 128 + lane * 8);
    float4 rb = ld4(r2 + (size_t)n * 128 + lane * 8 + 4);
    float4 ba = ld4(b2 + lane * 8);
    float4 bb = ld4(b2 + lane * 8 + 4);
    float rr[8] = {ra.x, ra.y, ra.z, ra.w, rb.x, rb.y, rb.z, rb.w};
    float bc[8] = {ba.x, ba.y, ba.z, ba.w, bb.x, bb.y, bb.z, bb.w};
    short8 o;
    #pragma unroll
    for (int i = 0; i < 8; ++i)
        o[i] = f2bf(fmaxf((a0[i] + a1[i]) * d + rr[i] + bc[i], 0.0f));
    *(short8*)(h2 + (size_t)n * 128 + lane * 8) = o;
}

// ---------------- gather 3 (fused combine + split write): out = mean-gather(tml) + rml + bias ----------------
__global__ __launch_bounds__(256) void gather3_kernel(
    const ushort_t* __restrict__ tml, const float* __restrict__ rml,
    const int* __restrict__ row_ptr, const int* __restrict__ eidx,
    const float* __restrict__ dinv, const float* __restrict__ bmu,
    const float* __restrict__ bls, float* __restrict__ out) {
    const int lane = threadIdx.x & 3;        // 4 lanes/node, 8 ch each
    const int nl = threadIdx.x >> 2;
    const int n = blockIdx.x * 64 + nl;
    if (n >= N_NODES) return;
    const int beg = row_ptr[n], end = row_ptr[n + 1];
    float a0[8] = {0,0,0,0,0,0,0,0}, a1[8] = {0,0,0,0,0,0,0,0};
    int j = beg;
    for (; j + 1 < end; j += 2) {
        int s0 = eidx[j], s1 = eidx[j + 1];
        short8 v0 = *(const short8*)(tml + (size_t)s0 * 32 + lane * 8);
        short8 v1 = *(const short8*)(tml + (size_t)s1 * 32 + lane * 8);
        #pragma unroll
        for (int i = 0; i < 8; ++i) { a0[i] += bf2f((ushort_t)v0[i]); a1[i] += bf2f((ushort_t)v1[i]); }
    }
    if (j < end) {
        int s0 = eidx[j];
        short8 v0 = *(const short8*)(tml + (size_t)s0 * 32 + lane * 8);
        #pragma unroll
        for (int i = 0; i < 8; ++i) a0[i] += bf2f((ushort_t)v0[i]);
    }
    float d = dinv[n];
    const float* bias = (lane < 2) ? (bmu + lane * 8) : (bls + (lane - 2) * 8);
    float4 ra = ld4(rml + (size_t)n * 32 + lane * 8);
    float4 rb = ld4(rml + (size_t)n * 32 + lane * 8 + 4);
    float4 ba = ld4(bias);
    float4 bb = ld4(bias + 4);
    float rr[8] = {ra.x, ra.y, ra.z, ra.w, rb.x, rb.y, rb.z, rb.w};
    float bc[8] = {ba.x, ba.y, ba.z, ba.w, bb.x, bb.y, bb.z, bb.w};
    float res[8];
    #pragma unroll
    for (int i = 0; i < 8; ++i) res[i] = (a0[i] + a1[i]) * d + rr[i] + bc[i];
    float* base = (lane < 2) ? (out + (size_t)n * 16 + lane * 8)
                             : (out + 800000u + (size_t)n * 16 + (lane - 2) * 8);
    *(float4*)(base) = make_float4(res[0], res[1], res[2], res[3]);
    *(float4*)(base + 4) = make_float4(res[4], res[5], res[6], res[7]);
}

extern "C" void kernel_launch(void* const* d_in, const int* in_sizes, int n_in,
                              void* d_out, int out_size, void* d_ws, size_t ws_size,
                              hipStream_t stream) {
    const float* x       = (const float*)d_in[0];
    const float* W1_rel  = (const float*)d_in[1];
    const float* b1      = (const float*)d_in[2];
    const float* W1_root = (const float*)d_in[3];
    const float* W2_rel  = (const float*)d_in[4];
    const float* b2      = (const float*)d_in[5];
    const float* W2_root = (const float*)d_in[6];
    const float* Wmu_rel = (const float*)d_in[7];
    const float* bmu     = (const float*)d_in[8];
    const float* Wmu_root= (const float*)d_in[9];
    const float* Wls_rel = (const float*)d_in[10];
    const float* bls     = (const float*)d_in[11];
    const float* Wls_root= (const float*)d_in[12];
    const int*   ei      = (const int*)d_in[13];
    const int* src = ei;
    const int* dst = ei + N_EDGES;

    // ---- workspace layout ----
    int*   cnt     = (int*)d_ws;               // 50,000
    int*   row_ptr = cnt + 50000;              // 50,001
    int*   cursor  = row_ptr + 50001;          // 50,000
    int*   eidx    = cursor + 50000;           // 800,000 (pad to 950,056 ints)
    float* dinv    = (float*)d_ws + 950056;    // 50,000 -> 1,000,056 floats
    ushort_t* ub   = (ushort_t*)((float*)d_ws + 1000056);
    ushort_t* ax   = ub;                       //  6,400,000  [N,128] bf16: [agg | x]
    ushort_t* h1   = ax + 6400000;             // 12,800,000  [N,256]
    ushort_t* t2   = h1 + 12800000;            //  6,400,000  [N,128]
    ushort_t* h2   = t2 + 6400000;             //  6,400,000  [N,128]
    ushort_t* tml  = h2 + 6400000;             //  1,600,000  [N,32]
    ushort_t* B1t  = tml + 1600000;            //     32,768
    ushort_t* B2t  = B1t + 32768;              //     65,536
    ushort_t* B3t  = B2t + 65536;              //      8,192
    float* r2      = (float*)(B3t + 8192);     //  6,400,000  [N,128] f32
    float* rml     = r2 + 6400000;             //  1,600,000  [N,32]  f32
    float* out     = (float*)d_out;

    // ---- CSR build + conversions ----
    hipMemsetAsync(cnt, 0, 50000 * sizeof(int), stream);
    hist_kernel<<<3125, 256, 0, stream>>>(dst, cnt);
    scan_kernel<<<1, 1024, 0, stream>>>(cnt, row_ptr, cursor, dinv);
    fill_kernel<<<3125, 256, 0, stream>>>(src, dst, cursor, eidx);
    cvt_x_kernel<<<1563, 256, 0, stream>>>(x, ax);
    cvt_w_kernel<<<416, 256, 0, stream>>>(W1_rel, W1_root, W2_rel, W2_root,
                                          Wmu_rel, Wls_rel, Wmu_root, Wls_root,
                                          B1t, B2t, B3t);

    // ---- layer 1 ----
    gather1_kernel<<<1563, 256, 0, stream>>>(row_ptr, eidx, dinv, ax);
    gemm1_mfma<<<dim3(782, 4), 256, 0, stream>>>(ax, B1t, b1, h1);

    // ---- layer 2 ----
    gemm2_mfma<<<dim3(782, 4), 256, 0, stream>>>(h1, B2t, t2, r2);
    gather2_kernel<<<3125, 256, 0, stream>>>(t2, r2, row_ptr, eidx, dinv, b2, h2);

    // ---- mu / logstd ----
    gemm3_mfma<<<dim3(782, 1), 256, 0, stream>>>(h2, B3t, tml, rml);
    gather3_kernel<<<782, 256, 0, stream>>>(tml, rml, row_ptr, eidx, dinv, bmu, bls, out);
}

// Round 4
// 331.128 us; speedup vs baseline: 8.1995x; 1.2563x over previous
//
#include <hip/hip_runtime.h>

#define N_NODES 50000
#define N_EDGES 800000
#define SCAN_NBLK 49  // ceil(50000/1024)

typedef unsigned short ushort_t;
typedef short short8 __attribute__((ext_vector_type(8)));
typedef float floatx4 __attribute__((ext_vector_type(4)));

__device__ __forceinline__ float bf2f(ushort_t u) {
    unsigned v = ((unsigned)u) << 16;
    return __builtin_bit_cast(float, v);
}
__device__ __forceinline__ ushort_t f2bf(float f) {
    unsigned u = __builtin_bit_cast(unsigned, f);
    unsigned r = (u + 0x7FFFu + ((u >> 16) & 1u)) >> 16;  // RNE
    return (ushort_t)r;
}
__device__ __forceinline__ float4 ld4(const float* p) { return *(const float4*)p; }

// ---------------- CSR build ----------------
__global__ void hist_kernel(const int* __restrict__ dst, int* __restrict__ cnt) {
    int i = blockIdx.x * blockDim.x + threadIdx.x;
    if (i < N_EDGES) atomicAdd(&cnt[dst[i]], 1);
}

// phase A: per-1024-chunk sums
__global__ __launch_bounds__(256) void scan_sums_kernel(const int* __restrict__ cnt,
                                                        int* __restrict__ bsum) {
    __shared__ int red[256];
    const int tid = threadIdx.x;
    const int base = blockIdx.x * 1024;
    int s = 0;
    #pragma unroll
    for (int j = 0; j < 4; ++j) {
        int i = base + j * 256 + tid;
        if (i < N_NODES) s += cnt[i];
    }
    red[tid] = s;
    __syncthreads();
    #pragma unroll
    for (int off = 128; off > 0; off >>= 1) {
        if (tid < off) red[tid] += red[tid + off];
        __syncthreads();
    }
    if (tid == 0) bsum[blockIdx.x] = red[0];
}

// phase B: exclusive scan of 49 block sums (one 64-thread block)
__global__ __launch_bounds__(64) void scan_offs_kernel(const int* __restrict__ bsum,
                                                       int* __restrict__ boffs) {
    __shared__ int sm[64];
    const int tid = threadIdx.x;
    int orig = (tid < SCAN_NBLK) ? bsum[tid] : 0;
    sm[tid] = orig;
    __syncthreads();
    #pragma unroll
    for (int off = 1; off < 64; off <<= 1) {
        int t = (tid >= off) ? sm[tid - off] : 0;
        __syncthreads();
        sm[tid] += t;
        __syncthreads();
    }
    if (tid < SCAN_NBLK) boffs[tid] = sm[tid] - orig;
}

// phase C: block-local scan + apply offset; write row_ptr/cursor/dinv
__global__ __launch_bounds__(256) void scan_apply_kernel(
    const int* __restrict__ cnt, const int* __restrict__ boffs,
    int* __restrict__ row_ptr, int* __restrict__ cursor, float* __restrict__ dinv) {
    __shared__ int sm[256];
    const int tid = threadIdx.x;
    const int i0 = blockIdx.x * 1024 + tid * 4;
    int c[4];
    int s = 0;
    #pragma unroll
    for (int j = 0; j < 4; ++j) {
        int i = i0 + j;
        c[j] = (i < N_NODES) ? cnt[i] : 0;
        s += c[j];
    }
    sm[tid] = s;
    __syncthreads();
    #pragma unroll
    for (int off = 1; off < 256; off <<= 1) {
        int t = (tid >= off) ? sm[tid - off] : 0;
        __syncthreads();
        sm[tid] += t;
        __syncthreads();
    }
    int exc = sm[tid] - s + boffs[blockIdx.x];
    #pragma unroll
    for (int j = 0; j < 4; ++j) {
        int i = i0 + j;
        if (i < N_NODES) {
            row_ptr[i] = exc;
            cursor[i] = exc;
            dinv[i] = c[j] > 0 ? 1.0f / (float)c[j] : 0.0f;
            exc += c[j];
        }
    }
    if (blockIdx.x == 0 && tid == 0) row_ptr[N_NODES] = N_EDGES;
}

__global__ void fill_kernel(const int* __restrict__ src, const int* __restrict__ dst,
                            int* __restrict__ cursor, int* __restrict__ eidx) {
    int e = blockIdx.x * blockDim.x + threadIdx.x;
    if (e < N_EDGES) {
        int slot = atomicAdd(&cursor[dst[e]], 1);
        eidx[slot] = src[e];
    }
}

// ---------------- conversions ----------------
// ax[n, 64:128] = bf16(x[n, :])   (ax is [N_NODES, 128] bf16)
__global__ __launch_bounds__(256) void cvt_x_kernel(const float* __restrict__ x,
                                                    ushort_t* __restrict__ ax) {
    int idx = blockIdx.x * blockDim.x + threadIdx.x;
    if (idx >= N_NODES * 8) return;
    int n = idx >> 3, c = (idx & 7) * 8;
    float4 v0 = ld4(x + (size_t)n * 64 + c);
    float4 v1 = ld4(x + (size_t)n * 64 + c + 4);
    short8 o;
    o[0] = f2bf(v0.x); o[1] = f2bf(v0.y); o[2] = f2bf(v0.z); o[3] = f2bf(v0.w);
    o[4] = f2bf(v1.x); o[5] = f2bf(v1.y); o[6] = f2bf(v1.z); o[7] = f2bf(v1.w);
    *(short8*)(ax + (size_t)n * 128 + 64 + c) = o;
}

// Build transposed bf16 weight mats:
// B1t[256 n][128 k]: k<64 -> W1_rel[k][n], else W1_root[k-64][n]
// B2t[256 n][256 k]: n<128 -> W2_rel[k][n], else W2_root[k][n-128]
// B3t[64 n][128 k]:  n>>4 selects {Wmu_rel, Wls_rel, Wmu_root, Wls_root}[k][n&15]
__global__ __launch_bounds__(256) void cvt_w_kernel(
    const float* __restrict__ W1_rel, const float* __restrict__ W1_root,
    const float* __restrict__ W2_rel, const float* __restrict__ W2_root,
    const float* __restrict__ Wmu_rel, const float* __restrict__ Wls_rel,
    const float* __restrict__ Wmu_root, const float* __restrict__ Wls_root,
    ushort_t* __restrict__ B1t, ushort_t* __restrict__ B2t, ushort_t* __restrict__ B3t) {
    int idx = blockIdx.x * blockDim.x + threadIdx.x;
    if (idx < 32768) {
        int n = idx >> 7, k = idx & 127;
        float v = (k < 64) ? W1_rel[k * 256 + n] : W1_root[(k - 64) * 256 + n];
        B1t[idx] = f2bf(v);
    } else if (idx < 98304) {
        int j = idx - 32768;
        int n = j >> 8, k = j & 255;
        float v = (n < 128) ? W2_rel[k * 128 + n] : W2_root[k * 128 + (n - 128)];
        B2t[j] = f2bf(v);
    } else if (idx < 106496) {
        int j = idx - 98304;
        int n = j >> 7, k = j & 127;
        const float* W = (n < 16) ? Wmu_rel : (n < 32) ? Wls_rel : (n < 48) ? Wmu_root : Wls_root;
        B3t[j] = f2bf(W[k * 16 + (n & 15)]);
    }
}

// ---------------- gather 1: ax[:, 0:64] = mean-gather of ax[:, 64:128] ----------------
__global__ __launch_bounds__(256) void gather1_kernel(
    const int* __restrict__ row_ptr, const int* __restrict__ eidx,
    const float* __restrict__ dinv, ushort_t* __restrict__ ax) {
    const int lane = threadIdx.x & 7;        // 8 lanes/node, 8 ch each
    const int nl = threadIdx.x >> 3;
    const int n = blockIdx.x * 32 + nl;
    if (n >= N_NODES) return;
    const int beg = row_ptr[n], end = row_ptr[n + 1];
    float a0[8] = {0,0,0,0,0,0,0,0}, a1[8] = {0,0,0,0,0,0,0,0};
    int j = beg;
    for (; j + 1 < end; j += 2) {
        int s0 = eidx[j], s1 = eidx[j + 1];
        short8 v0 = *(const short8*)(ax + (size_t)s0 * 128 + 64 + lane * 8);
        short8 v1 = *(const short8*)(ax + (size_t)s1 * 128 + 64 + lane * 8);
        #pragma unroll
        for (int i = 0; i < 8; ++i) { a0[i] += bf2f((ushort_t)v0[i]); a1[i] += bf2f((ushort_t)v1[i]); }
    }
    if (j < end) {
        int s0 = eidx[j];
        short8 v0 = *(const short8*)(ax + (size_t)s0 * 128 + 64 + lane * 8);
        #pragma unroll
        for (int i = 0; i < 8; ++i) a0[i] += bf2f((ushort_t)v0[i]);
    }
    float d = dinv[n];
    short8 o;
    #pragma unroll
    for (int i = 0; i < 8; ++i) o[i] = f2bf((a0[i] + a1[i]) * d);
    *(short8*)(ax + (size_t)n * 128 + lane * 8) = o;
}

// ---------------- MFMA GEMMs ----------------
// Each block: 4 waves x 16 rows = 64 rows of M; one 64-col N-tile (blockIdx.y).
// A frag: lane holds A[m=lane&15][k=quad*8+j]; B frag from Bt LDS (row=n, contiguous k);
// C/D: col=lane&15, row=quad*4+reg.

// gemm1: h1 = relu(ax @ [W1_rel;W1_root] + b1), A=[50000,128] bf16, N=256
__global__ __launch_bounds__(256) void gemm1_mfma(
    const ushort_t* __restrict__ A, const ushort_t* __restrict__ Bt,
    const float* __restrict__ b1, ushort_t* __restrict__ h1) {
    constexpr int K = 128, KP = K + 8;
    __shared__ ushort_t Bs[64 * KP];
    const int tid = threadIdx.x;
    const int w = tid >> 6, lane = tid & 63;
    const int ln = lane & 15, quad = lane >> 4;
    const int ny = blockIdx.y;
    const int rowbase = blockIdx.x * 64 + w * 16;
    for (int i = tid; i < 64 * K / 8; i += 256) {
        int row = i / (K / 8), off = i % (K / 8);
        *(short8*)(Bs + row * KP + off * 8) = *(const short8*)(Bt + (size_t)(ny * 64 + row) * K + off * 8);
    }
    __syncthreads();
    int r = rowbase + ln; if (r > N_NODES - 1) r = N_NODES - 1;
    short8 a[4];
    #pragma unroll
    for (int s = 0; s < 4; ++s)
        a[s] = *(const short8*)(A + (size_t)r * K + s * 32 + quad * 8);
    floatx4 acc[4] = {};
    #pragma unroll
    for (int f = 0; f < 4; ++f) {
        const ushort_t* bp = Bs + (f * 16 + ln) * KP + quad * 8;
        #pragma unroll
        for (int s = 0; s < 4; ++s) {
            short8 b = *(const short8*)(bp + s * 32);
            acc[f] = __builtin_amdgcn_mfma_f32_16x16x32_bf16(a[s], b, acc[f], 0, 0, 0);
        }
    }
    const int r0 = rowbase + quad * 4;
    #pragma unroll
    for (int f = 0; f < 4; ++f) {
        int n = ny * 64 + f * 16 + ln;
        float bias = b1[n];
        #pragma unroll
        for (int g = 0; g < 4; ++g) {
            int rr = r0 + g;
            if (rr >= N_NODES) continue;
            h1[(size_t)rr * 256 + n] = f2bf(fmaxf(acc[f][g] + bias, 0.0f));
        }
    }
}

// gemm2: [t2 | r2] = h1 @ [W2_rel | W2_root]; t2 bf16 (cols 0-127), r2 fp32 (cols 128-255)
__global__ __launch_bounds__(256) void gemm2_mfma(
    const ushort_t* __restrict__ A, const ushort_t* __restrict__ Bt,
    ushort_t* __restrict__ t2, float* __restrict__ r2) {
    constexpr int K = 256, KP = K + 8;
    __shared__ ushort_t Bs[64 * KP];
    const int tid = threadIdx.x;
    const int w = tid >> 6, lane = tid & 63;
    const int ln = lane & 15, quad = lane >> 4;
    const int ny = blockIdx.y;
    const int rowbase = blockIdx.x * 64 + w * 16;
    for (int i = tid; i < 64 * K / 8; i += 256) {
        int row = i / (K / 8), off = i % (K / 8);
        *(short8*)(Bs + row * KP + off * 8) = *(const short8*)(Bt + (size_t)(ny * 64 + row) * K + off * 8);
    }
    __syncthreads();
    int r = rowbase + ln; if (r > N_NODES - 1) r = N_NODES - 1;
    short8 a[8];
    #pragma unroll
    for (int s = 0; s < 8; ++s)
        a[s] = *(const short8*)(A + (size_t)r * K + s * 32 + quad * 8);
    floatx4 acc[4] = {};
    #pragma unroll
    for (int f = 0; f < 4; ++f) {
        const ushort_t* bp = Bs + (f * 16 + ln) * KP + quad * 8;
        #pragma unroll
        for (int s = 0; s < 8; ++s) {
            short8 b = *(const short8*)(bp + s * 32);
            acc[f] = __builtin_amdgcn_mfma_f32_16x16x32_bf16(a[s], b, acc[f], 0, 0, 0);
        }
    }
    const int r0 = rowbase + quad * 4;
    #pragma unroll
    for (int f = 0; f < 4; ++f) {
        int n = ny * 64 + f * 16 + ln;
        #pragma unroll
        for (int g = 0; g < 4; ++g) {
            int rr = r0 + g;
            if (rr >= N_NODES) continue;
            float v = acc[f][g];
            if (n < 128) t2[(size_t)rr * 128 + n] = f2bf(v);
            else r2[(size_t)rr * 128 + (n - 128)] = v;
        }
    }
}

// gemm3: [tml | rml] = h2 @ [Wmu_rel|Wls_rel|Wmu_root|Wls_root]; tml bf16 (0-31), rml fp32 (32-63)
__global__ __launch_bounds__(256) void gemm3_mfma(
    const ushort_t* __restrict__ A, const ushort_t* __restrict__ Bt,
    ushort_t* __restrict__ tml, float* __restrict__ rml) {
    constexpr int K = 128, KP = K + 8;
    __shared__ ushort_t Bs[64 * KP];
    const int tid = threadIdx.x;
    const int w = tid >> 6, lane = tid & 63;
    const int ln = lane & 15, quad = lane >> 4;
    const int rowbase = blockIdx.x * 64 + w * 16;
    for (int i = tid; i < 64 * K / 8; i += 256) {
        int row = i / (K / 8), off = i % (K / 8);
        *(short8*)(Bs + row * KP + off * 8) = *(const short8*)(Bt + (size_t)row * K + off * 8);
    }
    __syncthreads();
    int r = rowbase + ln; if (r > N_NODES - 1) r = N_NODES - 1;
    short8 a[4];
    #pragma unroll
    for (int s = 0; s < 4; ++s)
        a[s] = *(const short8*)(A + (size_t)r * K + s * 32 + quad * 8);
    floatx4 acc[4] = {};
    #pragma unroll
    for (int f = 0; f < 4; ++f) {
        const ushort_t* bp = Bs + (f * 16 + ln) * KP + quad * 8;
        #pragma unroll
        for (int s = 0; s < 4; ++s) {
            short8 b = *(const short8*)(bp + s * 32);
            acc[f] = __builtin_amdgcn_mfma_f32_16x16x32_bf16(a[s], b, acc[f], 0, 0, 0);
        }
    }
    const int r0 = rowbase + quad * 4;
    #pragma unroll
    for (int f = 0; f < 4; ++f) {
        int n = f * 16 + ln;
        #pragma unroll
        for (int g = 0; g < 4; ++g) {
            int rr = r0 + g;
            if (rr >= N_NODES) continue;
            float v = acc[f][g];
            if (n < 32) tml[(size_t)rr * 32 + n] = f2bf(v);
            else rml[(size_t)rr * 32 + (n - 32)] = v;
        }
    }
}

// ---------------- gather 2 (fused combine): h2 = relu(mean-gather(t2) + r2 + b2), bf16 out ----------------
__global__ __launch_bounds__(256) void gather2_kernel(
    const ushort_t* __restrict__ t2, const float* __restrict__ r2,
    const int* __restrict__ row_ptr, const int* __restrict__ eidx,
    const float* __restrict__ dinv, const float* __restrict__ b2,
    ushort_t* __restrict__ h2) {
    const int lane = threadIdx.x & 15;       // 16 lanes/node, 8 ch each
    const int nl = threadIdx.x >> 4;
    const int n = blockIdx.x * 16 + nl;      // 3125*16 = 50000 exact
    const int beg = row_ptr[n], end = row_ptr[n + 1];
    float a0[8] = {0,0,0,0,0,0,0,0}, a1[8] = {0,0,0,0,0,0,0,0};
    int j = beg;
    for (; j + 1 < end; j += 2) {
        int s0 = eidx[j], s1 = eidx[j + 1];
        short8 v0 = *(const short8*)(t2 + (size_t)s0 * 128 + lane * 8);
        short8 v1 = *(const short8*)(t2 + (size_t)s1 * 128 + lane * 8);
        #pragma unroll
        for (int i = 0; i < 8; ++i) { a0[i] += bf2f((ushort_t)v0[i]); a1[i] += bf2f((ushort_t)v1[i]); }
    }
    if (j < end) {
        int s0 = eidx[j];
        short8 v0 = *(const short8*)(t2 + (size_t)s0 * 128 + lane * 8);
        #pragma unroll
        for (int i = 0; i < 8; ++i) a0[i] += bf2f((ushort_t)v0[i]);
    }
    float d = dinv[n];
    float4 ra = ld4(r2 + (size_t)n * 128 + lane * 8);
    float4 rb = ld4(r2 + (size_t)n * 128 + lane * 8 + 4);
    float4 ba = ld4(b2 + lane * 8);
    float4 bb = ld4(b2 + lane * 8 + 4);
    float rr[8] = {ra.x, ra.y, ra.z, ra.w, rb.x, rb.y, rb.z, rb.w};
    float bc[8] = {ba.x, ba.y, ba.z, ba.w, bb.x, bb.y, bb.z, bb.w};
    short8 o;
    #pragma unroll
    for (int i = 0; i < 8; ++i)
        o[i] = f2bf(fmaxf((a0[i] + a1[i]) * d + rr[i] + bc[i], 0.0f));
    *(short8*)(h2 + (size_t)n * 128 + lane * 8) = o;
}

// ---------------- gather 3 (fused combine + split write): out = mean-gather(tml) + rml + bias ----------------
__global__ __launch_bounds__(256) void gather3_kernel(
    const ushort_t* __restrict__ tml, const float* __restrict__ rml,
    const int* __restrict__ row_ptr, const int* __restrict__ eidx,
    const float* __restrict__ dinv, const float* __restrict__ bmu,
    const float* __restrict__ bls, float* __restrict__ out) {
    const int lane = threadIdx.x & 3;        // 4 lanes/node, 8 ch each
    const int nl = threadIdx.x >> 2;
    const int n = blockIdx.x * 64 + nl;
    if (n >= N_NODES) return;
    const int beg = row_ptr[n], end = row_ptr[n + 1];
    float a0[8] = {0,0,0,0,0,0,0,0}, a1[8] = {0,0,0,0,0,0,0,0};
    int j = beg;
    for (; j + 1 < end; j += 2) {
        int s0 = eidx[j], s1 = eidx[j + 1];
        short8 v0 = *(const short8*)(tml + (size_t)s0 * 32 + lane * 8);
        short8 v1 = *(const short8*)(tml + (size_t)s1 * 32 + lane * 8);
        #pragma unroll
        for (int i = 0; i < 8; ++i) { a0[i] += bf2f((ushort_t)v0[i]); a1[i] += bf2f((ushort_t)v1[i]); }
    }
    if (j < end) {
        int s0 = eidx[j];
        short8 v0 = *(const short8*)(tml + (size_t)s0 * 32 + lane * 8);
        #pragma unroll
        for (int i = 0; i < 8; ++i) a0[i] += bf2f((ushort_t)v0[i]);
    }
    float d = dinv[n];
    const float* bias = (lane < 2) ? (bmu + lane * 8) : (bls + (lane - 2) * 8);
    float4 ra = ld4(rml + (size_t)n * 32 + lane * 8);
    float4 rb = ld4(rml + (size_t)n * 32 + lane * 8 + 4);
    float4 ba = ld4(bias);
    float4 bb = ld4(bias + 4);
    float rr[8] = {ra.x, ra.y, ra.z, ra.w, rb.x, rb.y, rb.z, rb.w};
    float bc[8] = {ba.x, ba.y, ba.z, ba.w, bb.x, bb.y, bb.z, bb.w};
    float res[8];
    #pragma unroll
    for (int i = 0; i < 8; ++i) res[i] = (a0[i] + a1[i]) * d + rr[i] + bc[i];
    float* base = (lane < 2) ? (out + (size_t)n * 16 + lane * 8)
                             : (out + 800000u + (size_t)n * 16 + (lane - 2) * 8);
    *(float4*)(base) = make_float4(res[0], res[1], res[2], res[3]);
    *(float4*)(base + 4) = make_float4(res[4], res[5], res[6], res[7]);
}

extern "C" void kernel_launch(void* const* d_in, const int* in_sizes, int n_in,
                              void* d_out, int out_size, void* d_ws, size_t ws_size,
                              hipStream_t stream) {
    const float* x       = (const float*)d_in[0];
    const float* W1_rel  = (const float*)d_in[1];
    const float* b1      = (const float*)d_in[2];
    const float* W1_root = (const float*)d_in[3];
    const float* W2_rel  = (const float*)d_in[4];
    const float* b2      = (const float*)d_in[5];
    const float* W2_root = (const float*)d_in[6];
    const float* Wmu_rel = (const float*)d_in[7];
    const float* bmu     = (const float*)d_in[8];
    const float* Wmu_root= (const float*)d_in[9];
    const float* Wls_rel = (const float*)d_in[10];
    const float* bls     = (const float*)d_in[11];
    const float* Wls_root= (const float*)d_in[12];
    const int*   ei      = (const int*)d_in[13];
    const int* src = ei;
    const int* dst = ei + N_EDGES;

    // ---- workspace layout ----
    int*   cnt     = (int*)d_ws;               // 50,000
    int*   row_ptr = cnt + 50000;              // 50,001
    int*   cursor  = row_ptr + 50001;          // 50,000
    int*   eidx    = cursor + 50000;           // 800,000
    int*   bsum    = eidx + 800000;            // 64
    int*   boffs   = bsum + 64;                // 64   (-> 950,179 ints; pad to 950,184)
    float* dinv    = (float*)d_ws + 950184;    // 50,000 -> 1,000,184 floats
    ushort_t* ub   = (ushort_t*)((float*)d_ws + 1000184);
    ushort_t* ax   = ub;                       //  6,400,000  [N,128] bf16: [agg | x]
    ushort_t* h1   = ax + 6400000;             // 12,800,000  [N,256]
    ushort_t* t2   = h1 + 12800000;            //  6,400,000  [N,128]
    ushort_t* h2   = t2 + 6400000;             //  6,400,000  [N,128]
    ushort_t* tml  = h2 + 6400000;             //  1,600,000  [N,32]
    ushort_t* B1t  = tml + 1600000;            //     32,768
    ushort_t* B2t  = B1t + 32768;              //     65,536
    ushort_t* B3t  = B2t + 65536;              //      8,192
    float* r2      = (float*)(B3t + 8192);     //  6,400,000  [N,128] f32
    float* rml     = r2 + 6400000;             //  1,600,000  [N,32]  f32
    float* out     = (float*)d_out;

    // ---- CSR build + conversions ----
    hipMemsetAsync(cnt, 0, 50000 * sizeof(int), stream);
    hist_kernel<<<3125, 256, 0, stream>>>(dst, cnt);
    scan_sums_kernel<<<SCAN_NBLK, 256, 0, stream>>>(cnt, bsum);
    scan_offs_kernel<<<1, 64, 0, stream>>>(bsum, boffs);
    scan_apply_kernel<<<SCAN_NBLK, 256, 0, stream>>>(cnt, boffs, row_ptr, cursor, dinv);
    fill_kernel<<<3125, 256, 0, stream>>>(src, dst, cursor, eidx);
    cvt_x_kernel<<<1563, 256, 0, stream>>>(x, ax);
    cvt_w_kernel<<<416, 256, 0, stream>>>(W1_rel, W1_root, W2_rel, W2_root,
                                          Wmu_rel, Wls_rel, Wmu_root, Wls_root,
                                          B1t, B2t, B3t);

    // ---- layer 1 ----
    gather1_kernel<<<1563, 256, 0, stream>>>(row_ptr, eidx, dinv, ax);
    gemm1_mfma<<<dim3(782, 4), 256, 0, stream>>>(ax, B1t, b1, h1);

    // ---- layer 2 ----
    gemm2_mfma<<<dim3(782, 4), 256, 0, stream>>>(h1, B2t, t2, r2);
    gather2_kernel<<<3125, 256, 0, stream>>>(t2, r2, row_ptr, eidx, dinv, b2, h2);

    // ---- mu / logstd ----
    gemm3_mfma<<<dim3(782, 1), 256, 0, stream>>>(h2, B3t, tml, rml);
    gather3_kernel<<<782, 256, 0, stream>>>(tml, rml, row_ptr, eidx, dinv, bmu, bls, out);
}

// Round 5
// 288.069 us; speedup vs baseline: 9.4251x; 1.1495x over previous
//
#include <hip/hip_runtime.h>

#define N_NODES 50000
#define N_EDGES 800000
#define NBUCK 196       // ceil(50000/256) buckets of 256 nodes
#define PBLK 391        // ceil(800000/2048) partition blocks

typedef unsigned short ushort_t;
typedef short short8 __attribute__((ext_vector_type(8)));
typedef float floatx4 __attribute__((ext_vector_type(4)));

__device__ __forceinline__ float bf2f(ushort_t u) {
    unsigned v = ((unsigned)u) << 16;
    return __builtin_bit_cast(float, v);
}
__device__ __forceinline__ ushort_t f2bf(float f) {
    unsigned u = __builtin_bit_cast(unsigned, f);
    unsigned r = (u + 0x7FFFu + ((u >> 16) & 1u)) >> 16;  // RNE
    return (ushort_t)r;
}
__device__ __forceinline__ float4 ld4(const float* p) { return *(const float4*)p; }

// ---------------- CSR build: two-level counting sort ----------------
// bucket b = dst >> 8 covers nodes [b*256, b*256+256)

__global__ __launch_bounds__(256) void bucket_hist_kernel(const int* __restrict__ dst,
                                                          int* __restrict__ bcnt) {
    __shared__ int h[NBUCK];
    const int tid = threadIdx.x;
    for (int i = tid; i < NBUCK; i += 256) h[i] = 0;
    __syncthreads();
    const int base = blockIdx.x * 2048;
    #pragma unroll
    for (int j = 0; j < 8; ++j) {
        int e = base + j * 256 + tid;
        if (e < N_EDGES) atomicAdd(&h[dst[e] >> 8], 1);
    }
    __syncthreads();
    for (int i = tid; i < NBUCK; i += 256)
        if (h[i]) atomicAdd(&bcnt[i], h[i]);
}

__global__ __launch_bounds__(256) void bucket_scan_kernel(const int* __restrict__ bcnt,
                                                          int* __restrict__ boffs,
                                                          int* __restrict__ bcursor) {
    __shared__ int sm[256];
    const int tid = threadIdx.x;
    int v = (tid < NBUCK) ? bcnt[tid] : 0;
    sm[tid] = v;
    __syncthreads();
    #pragma unroll
    for (int off = 1; off < 256; off <<= 1) {
        int t = (tid >= off) ? sm[tid - off] : 0;
        __syncthreads();
        sm[tid] += t;
        __syncthreads();
    }
    int exc = sm[tid] - v;
    if (tid < NBUCK) { boffs[tid] = exc; bcursor[tid] = exc; }
    if (tid == 0) boffs[NBUCK] = N_EDGES;
}

// partition edges into bucket-contiguous pairbuf; record = (dstlow<<16)|src (src<65536)
__global__ __launch_bounds__(256) void partition_kernel(
    const int* __restrict__ src, const int* __restrict__ dst,
    int* __restrict__ bcursor, unsigned* __restrict__ pairbuf) {
    __shared__ int h[NBUCK];
    __shared__ int cur[NBUCK];
    const int tid = threadIdx.x;
    for (int i = tid; i < NBUCK; i += 256) h[i] = 0;
    __syncthreads();
    const int base = blockIdx.x * 2048;
    int d[8];
    #pragma unroll
    for (int j = 0; j < 8; ++j) {
        int e = base + j * 256 + tid;
        if (e < N_EDGES) { d[j] = dst[e]; atomicAdd(&h[d[j] >> 8], 1); }
        else d[j] = -1;
    }
    __syncthreads();
    for (int i = tid; i < NBUCK; i += 256) {
        int c = h[i];
        cur[i] = c ? atomicAdd(&bcursor[i], c) : 0;
    }
    __syncthreads();
    #pragma unroll
    for (int j = 0; j < 8; ++j) {
        int e = base + j * 256 + tid;
        if (e < N_EDGES) {
            int dd = d[j];
            int slot = atomicAdd(&cur[dd >> 8], 1);
            pairbuf[slot] = (unsigned)src[e] | ((unsigned)(dd & 255) << 16);
        }
    }
}

// per-bucket: node histogram + scan -> row_ptr/dinv; LDS-cursor fill of 16-bit eidx
__global__ __launch_bounds__(256) void fill_bucket_kernel(
    const unsigned* __restrict__ pairbuf, const int* __restrict__ boffs,
    int* __restrict__ row_ptr, float* __restrict__ dinv, ushort_t* __restrict__ eidx) {
    __shared__ int h[256];
    __shared__ int sm[256];
    __shared__ int cur[256];
    const int b = blockIdx.x, tid = threadIdx.x;
    const int beg = boffs[b], end = boffs[b + 1];
    h[tid] = 0;
    __syncthreads();
    for (int i = beg + tid; i < end; i += 256)
        atomicAdd(&h[pairbuf[i] >> 16], 1);
    __syncthreads();
    int c = h[tid];
    sm[tid] = c;
    __syncthreads();
    #pragma unroll
    for (int off = 1; off < 256; off <<= 1) {
        int t = (tid >= off) ? sm[tid - off] : 0;
        __syncthreads();
        sm[tid] += t;
        __syncthreads();
    }
    int exc = beg + sm[tid] - c;
    int node = b * 256 + tid;
    if (node < N_NODES) {
        row_ptr[node] = exc;
        dinv[node] = c > 0 ? 1.0f / (float)c : 0.0f;
    }
    cur[tid] = exc;
    __syncthreads();
    for (int i = beg + tid; i < end; i += 256) {
        unsigned v = pairbuf[i];
        int slot = atomicAdd(&cur[v >> 16], 1);
        eidx[slot] = (ushort_t)(v & 0xFFFFu);
    }
    if (b == 0 && tid == 0) row_ptr[N_NODES] = N_EDGES;
}

// ---------------- conversions ----------------
__global__ __launch_bounds__(256) void cvt_x_kernel(const float* __restrict__ x,
                                                    ushort_t* __restrict__ ax) {
    int idx = blockIdx.x * blockDim.x + threadIdx.x;
    if (idx >= N_NODES * 8) return;
    int n = idx >> 3, c = (idx & 7) * 8;
    float4 v0 = ld4(x + (size_t)n * 64 + c);
    float4 v1 = ld4(x + (size_t)n * 64 + c + 4);
    short8 o;
    o[0] = f2bf(v0.x); o[1] = f2bf(v0.y); o[2] = f2bf(v0.z); o[3] = f2bf(v0.w);
    o[4] = f2bf(v1.x); o[5] = f2bf(v1.y); o[6] = f2bf(v1.z); o[7] = f2bf(v1.w);
    *(short8*)(ax + (size_t)n * 128 + 64 + c) = o;
}

// B1t[256 n][128 k]; B2t[256 n][256 k]; B3t[64 n][128 k] (see R3 comments)
__global__ __launch_bounds__(256) void cvt_w_kernel(
    const float* __restrict__ W1_rel, const float* __restrict__ W1_root,
    const float* __restrict__ W2_rel, const float* __restrict__ W2_root,
    const float* __restrict__ Wmu_rel, const float* __restrict__ Wls_rel,
    const float* __restrict__ Wmu_root, const float* __restrict__ Wls_root,
    ushort_t* __restrict__ B1t, ushort_t* __restrict__ B2t, ushort_t* __restrict__ B3t) {
    int idx = blockIdx.x * blockDim.x + threadIdx.x;
    if (idx < 32768) {
        int n = idx >> 7, k = idx & 127;
        float v = (k < 64) ? W1_rel[k * 256 + n] : W1_root[(k - 64) * 256 + n];
        B1t[idx] = f2bf(v);
    } else if (idx < 98304) {
        int j = idx - 32768;
        int n = j >> 8, k = j & 255;
        float v = (n < 128) ? W2_rel[k * 128 + n] : W2_root[k * 128 + (n - 128)];
        B2t[j] = f2bf(v);
    } else if (idx < 106496) {
        int j = idx - 98304;
        int n = j >> 7, k = j & 127;
        const float* W = (n < 16) ? Wmu_rel : (n < 32) ? Wls_rel : (n < 48) ? Wmu_root : Wls_root;
        B3t[j] = f2bf(W[k * 16 + (n & 15)]);
    }
}

// ---------------- gather 1: ax[:, 0:64] = mean-gather of ax[:, 64:128] ----------------
__global__ __launch_bounds__(256) void gather1_kernel(
    const int* __restrict__ row_ptr, const ushort_t* __restrict__ eidx,
    const float* __restrict__ dinv, ushort_t* __restrict__ ax) {
    const int lane = threadIdx.x & 7;
    const int nl = threadIdx.x >> 3;
    const int n = blockIdx.x * 32 + nl;
    if (n >= N_NODES) return;
    const int beg = row_ptr[n], end = row_ptr[n + 1];
    float a0[8] = {0,0,0,0,0,0,0,0}, a1[8] = {0,0,0,0,0,0,0,0};
    int j = beg;
    for (; j + 1 < end; j += 2) {
        int s0 = eidx[j], s1 = eidx[j + 1];
        short8 v0 = *(const short8*)(ax + (size_t)s0 * 128 + 64 + lane * 8);
        short8 v1 = *(const short8*)(ax + (size_t)s1 * 128 + 64 + lane * 8);
        #pragma unroll
        for (int i = 0; i < 8; ++i) { a0[i] += bf2f((ushort_t)v0[i]); a1[i] += bf2f((ushort_t)v1[i]); }
    }
    if (j < end) {
        int s0 = eidx[j];
        short8 v0 = *(const short8*)(ax + (size_t)s0 * 128 + 64 + lane * 8);
        #pragma unroll
        for (int i = 0; i < 8; ++i) a0[i] += bf2f((ushort_t)v0[i]);
    }
    float d = dinv[n];
    short8 o;
    #pragma unroll
    for (int i = 0; i < 8; ++i) o[i] = f2bf((a0[i] + a1[i]) * d);
    *(short8*)(ax + (size_t)n * 128 + lane * 8) = o;
}

// ---------------- MFMA GEMMs (layouts as R3) ----------------
__global__ __launch_bounds__(256) void gemm1_mfma(
    const ushort_t* __restrict__ A, const ushort_t* __restrict__ Bt,
    const float* __restrict__ b1, ushort_t* __restrict__ h1) {
    constexpr int K = 128, KP = K + 8;
    __shared__ ushort_t Bs[64 * KP];
    const int tid = threadIdx.x;
    const int w = tid >> 6, lane = tid & 63;
    const int ln = lane & 15, quad = lane >> 4;
    const int ny = blockIdx.y;
    const int rowbase = blockIdx.x * 64 + w * 16;
    for (int i = tid; i < 64 * K / 8; i += 256) {
        int row = i / (K / 8), off = i % (K / 8);
        *(short8*)(Bs + row * KP + off * 8) = *(const short8*)(Bt + (size_t)(ny * 64 + row) * K + off * 8);
    }
    __syncthreads();
    int r = rowbase + ln; if (r > N_NODES - 1) r = N_NODES - 1;
    short8 a[4];
    #pragma unroll
    for (int s = 0; s < 4; ++s)
        a[s] = *(const short8*)(A + (size_t)r * K + s * 32 + quad * 8);
    floatx4 acc[4] = {};
    #pragma unroll
    for (int f = 0; f < 4; ++f) {
        const ushort_t* bp = Bs + (f * 16 + ln) * KP + quad * 8;
        #pragma unroll
        for (int s = 0; s < 4; ++s) {
            short8 b = *(const short8*)(bp + s * 32);
            acc[f] = __builtin_amdgcn_mfma_f32_16x16x32_bf16(a[s], b, acc[f], 0, 0, 0);
        }
    }
    const int r0 = rowbase + quad * 4;
    #pragma unroll
    for (int f = 0; f < 4; ++f) {
        int n = ny * 64 + f * 16 + ln;
        float bias = b1[n];
        #pragma unroll
        for (int g = 0; g < 4; ++g) {
            int rr = r0 + g;
            if (rr >= N_NODES) continue;
            h1[(size_t)rr * 256 + n] = f2bf(fmaxf(acc[f][g] + bias, 0.0f));
        }
    }
}

__global__ __launch_bounds__(256) void gemm2_mfma(
    const ushort_t* __restrict__ A, const ushort_t* __restrict__ Bt,
    ushort_t* __restrict__ t2, float* __restrict__ r2) {
    constexpr int K = 256, KP = K + 8;
    __shared__ ushort_t Bs[64 * KP];
    const int tid = threadIdx.x;
    const int w = tid >> 6, lane = tid & 63;
    const int ln = lane & 15, quad = lane >> 4;
    const int ny = blockIdx.y;
    const int rowbase = blockIdx.x * 64 + w * 16;
    for (int i = tid; i < 64 * K / 8; i += 256) {
        int row = i / (K / 8), off = i % (K / 8);
        *(short8*)(Bs + row * KP + off * 8) = *(const short8*)(Bt + (size_t)(ny * 64 + row) * K + off * 8);
    }
    __syncthreads();
    int r = rowbase + ln; if (r > N_NODES - 1) r = N_NODES - 1;
    short8 a[8];
    #pragma unroll
    for (int s = 0; s < 8; ++s)
        a[s] = *(const short8*)(A + (size_t)r * K + s * 32 + quad * 8);
    floatx4 acc[4] = {};
    #pragma unroll
    for (int f = 0; f < 4; ++f) {
        const ushort_t* bp = Bs + (f * 16 + ln) * KP + quad * 8;
        #pragma unroll
        for (int s = 0; s < 8; ++s) {
            short8 b = *(const short8*)(bp + s * 32);
            acc[f] = __builtin_amdgcn_mfma_f32_16x16x32_bf16(a[s], b, acc[f], 0, 0, 0);
        }
    }
    const int r0 = rowbase + quad * 4;
    #pragma unroll
    for (int f = 0; f < 4; ++f) {
        int n = ny * 64 + f * 16 + ln;
        #pragma unroll
        for (int g = 0; g < 4; ++g) {
            int rr = r0 + g;
            if (rr >= N_NODES) continue;
            float v = acc[f][g];
            if (n < 128) t2[(size_t)rr * 128 + n] = f2bf(v);
            else r2[(size_t)rr * 128 + (n - 128)] = v;
        }
    }
}

__global__ __launch_bounds__(256) void gemm3_mfma(
    const ushort_t* __restrict__ A, const ushort_t* __restrict__ Bt,
    ushort_t* __restrict__ tml, float* __restrict__ rml) {
    constexpr int K = 128, KP = K + 8;
    __shared__ ushort_t Bs[64 * KP];
    const int tid = threadIdx.x;
    const int w = tid >> 6, lane = tid & 63;
    const int ln = lane & 15, quad = lane >> 4;
    const int rowbase = blockIdx.x * 64 + w * 16;
    for (int i = tid; i < 64 * K / 8; i += 256) {
        int row = i / (K / 8), off = i % (K / 8);
        *(short8*)(Bs + row * KP + off * 8) = *(const short8*)(Bt + (size_t)row * K + off * 8);
    }
    __syncthreads();
    int r = rowbase + ln; if (r > N_NODES - 1) r = N_NODES - 1;
    short8 a[4];
    #pragma unroll
    for (int s = 0; s < 4; ++s)
        a[s] = *(const short8*)(A + (size_t)r * K + s * 32 + quad * 8);
    floatx4 acc[4] = {};
    #pragma unroll
    for (int f = 0; f < 4; ++f) {
        const ushort_t* bp = Bs + (f * 16 + ln) * KP + quad * 8;
        #pragma unroll
        for (int s = 0; s < 4; ++s) {
            short8 b = *(const short8*)(bp + s * 32);
            acc[f] = __builtin_amdgcn_mfma_f32_16x16x32_bf16(a[s], b, acc[f], 0, 0, 0);
        }
    }
    const int r0 = rowbase + quad * 4;
    #pragma unroll
    for (int f = 0; f < 4; ++f) {
        int n = f * 16 + ln;
        #pragma unroll
        for (int g = 0; g < 4; ++g) {
            int rr = r0 + g;
            if (rr >= N_NODES) continue;
            float v = acc[f][g];
            if (n < 32) tml[(size_t)rr * 32 + n] = f2bf(v);
            else rml[(size_t)rr * 32 + (n - 32)] = v;
        }
    }
}

// ---------------- gather 2 (fused combine) ----------------
__global__ __launch_bounds__(256) void gather2_kernel(
    const ushort_t* __restrict__ t2, const float* __restrict__ r2,
    const int* __restrict__ row_ptr, const ushort_t* __restrict__ eidx,
    const float* __restrict__ dinv, const float* __restrict__ b2,
    ushort_t* __restrict__ h2) {
    const int lane = threadIdx.x & 15;
    const int nl = threadIdx.x >> 4;
    const int n = blockIdx.x * 16 + nl;
    const int beg = row_ptr[n], end = row_ptr[n + 1];
    float a0[8] = {0,0,0,0,0,0,0,0}, a1[8] = {0,0,0,0,0,0,0,0};
    int j = beg;
    for (; j + 1 < end; j += 2) {
        int s0 = eidx[j], s1 = eidx[j + 1];
        short8 v0 = *(const short8*)(t2 + (size_t)s0 * 128 + lane * 8);
        short8 v1 = *(const short8*)(t2 + (size_t)s1 * 128 + lane * 8);
        #pragma unroll
        for (int i = 0; i < 8; ++i) { a0[i] += bf2f((ushort_t)v0[i]); a1[i] += bf2f((ushort_t)v1[i]); }
    }
    if (j < end) {
        int s0 = eidx[j];
        short8 v0 = *(const short8*)(t2 + (size_t)s0 * 128 + lane * 8);
        #pragma unroll
        for (int i = 0; i < 8; ++i) a0[i] += bf2f((ushort_t)v0[i]);
    }
    float d = dinv[n];
    float4 ra = ld4(r2 + (size_t)n * 128 + lane * 8);
    float4 rb = ld4(r2 + (size_t)n * 128 + lane * 8 + 4);
    float4 ba = ld4(b2 + lane * 8);
    float4 bb = ld4(b2 + lane * 8 + 4);
    float rr[8] = {ra.x, ra.y, ra.z, ra.w, rb.x, rb.y, rb.z, rb.w};
    float bc[8] = {ba.x, ba.y, ba.z, ba.w, bb.x, bb.y, bb.z, bb.w};
    short8 o;
    #pragma unroll
    for (int i = 0; i < 8; ++i)
        o[i] = f2bf(fmaxf((a0[i] + a1[i]) * d + rr[i] + bc[i], 0.0f));
    *(short8*)(h2 + (size_t)n * 128 + lane * 8) = o;
}

// ---------------- gather 3 (fused combine + split write) ----------------
__global__ __launch_bounds__(256) void gather3_kernel(
    const ushort_t* __restrict__ tml, const float* __restrict__ rml,
    const int* __restrict__ row_ptr, const ushort_t* __restrict__ eidx,
    const float* __restrict__ dinv, const float* __restrict__ bmu,
    const float* __restrict__ bls, float* __restrict__ out) {
    const int lane = threadIdx.x & 3;
    const int nl = threadIdx.x >> 2;
    const int n = blockIdx.x * 64 + nl;
    if (n >= N_NODES) return;
    const int beg = row_ptr[n], end = row_ptr[n + 1];
    float a0[8] = {0,0,0,0,0,0,0,0}, a1[8] = {0,0,0,0,0,0,0,0};
    int j = beg;
    for (; j + 1 < end; j += 2) {
        int s0 = eidx[j], s1 = eidx[j + 1];
        short8 v0 = *(const short8*)(tml + (size_t)s0 * 32 + lane * 8);
        short8 v1 = *(const short8*)(tml + (size_t)s1 * 32 + lane * 8);
        #pragma unroll
        for (int i = 0; i < 8; ++i) { a0[i] += bf2f((ushort_t)v0[i]); a1[i] += bf2f((ushort_t)v1[i]); }
    }
    if (j < end) {
        int s0 = eidx[j];
        short8 v0 = *(const short8*)(tml + (size_t)s0 * 32 + lane * 8);
        #pragma unroll
        for (int i = 0; i < 8; ++i) a0[i] += bf2f((ushort_t)v0[i]);
    }
    float d = dinv[n];
    const float* bias = (lane < 2) ? (bmu + lane * 8) : (bls + (lane - 2) * 8);
    float4 ra = ld4(rml + (size_t)n * 32 + lane * 8);
    float4 rb = ld4(rml + (size_t)n * 32 + lane * 8 + 4);
    float4 ba = ld4(bias);
    float4 bb = ld4(bias + 4);
    float rr[8] = {ra.x, ra.y, ra.z, ra.w, rb.x, rb.y, rb.z, rb.w};
    float bc[8] = {ba.x, ba.y, ba.z, ba.w, bb.x, bb.y, bb.z, bb.w};
    float res[8];
    #pragma unroll
    for (int i = 0; i < 8; ++i) res[i] = (a0[i] + a1[i]) * d + rr[i] + bc[i];
    float* base = (lane < 2) ? (out + (size_t)n * 16 + lane * 8)
                             : (out + 800000u + (size_t)n * 16 + (lane - 2) * 8);
    *(float4*)(base) = make_float4(res[0], res[1], res[2], res[3]);
    *(float4*)(base + 4) = make_float4(res[4], res[5], res[6], res[7]);
}

extern "C" void kernel_launch(void* const* d_in, const int* in_sizes, int n_in,
                              void* d_out, int out_size, void* d_ws, size_t ws_size,
                              hipStream_t stream) {
    const float* x       = (const float*)d_in[0];
    const float* W1_rel  = (const float*)d_in[1];
    const float* b1      = (const float*)d_in[2];
    const float* W1_root = (const float*)d_in[3];
    const float* W2_rel  = (const float*)d_in[4];
    const float* b2      = (const float*)d_in[5];
    const float* W2_root = (const float*)d_in[6];
    const float* Wmu_rel = (const float*)d_in[7];
    const float* bmu     = (const float*)d_in[8];
    const float* Wmu_root= (const float*)d_in[9];
    const float* Wls_rel = (const float*)d_in[10];
    const float* bls     = (const float*)d_in[11];
    const float* Wls_root= (const float*)d_in[12];
    const int*   ei      = (const int*)d_in[13];
    const int* src = ei;
    const int* dst = ei + N_EDGES;

    // ---- workspace layout ----
    int*      bcnt    = (int*)d_ws;              //    256 (196 used)
    int*      boffs   = bcnt + 256;              //    256 (197 used)
    int*      bcursor = boffs + 256;             //    256
    int*      row_ptr = bcursor + 256;           // 50,001 -> pad 50,004
    unsigned* pairbuf = (unsigned*)(row_ptr + 50004);   // 800,000
    ushort_t* eidx    = (ushort_t*)(pairbuf + 800000);  // 800,000 ushorts = 400,000 ints
    float*    dinv    = (float*)(eidx + 800000);        // 50,000
    ushort_t* ub      = (ushort_t*)(dinv + 50000);
    ushort_t* ax   = ub;                       //  6,400,000  [N,128] bf16: [agg | x]
    ushort_t* h1   = ax + 6400000;             // 12,800,000  [N,256]
    ushort_t* t2   = h1 + 12800000;            //  6,400,000  [N,128]
    ushort_t* h2   = t2 + 6400000;             //  6,400,000  [N,128]
    ushort_t* tml  = h2 + 6400000;             //  1,600,000  [N,32]
    ushort_t* B1t  = tml + 1600000;            //     32,768
    ushort_t* B2t  = B1t + 32768;              //     65,536
    ushort_t* B3t  = B2t + 65536;              //      8,192
    float* r2      = (float*)(B3t + 8192);     //  6,400,000  [N,128] f32
    float* rml     = r2 + 6400000;             //  1,600,000  [N,32]  f32
    float* out     = (float*)d_out;

    // ---- CSR build (two-level counting sort) ----
    hipMemsetAsync(bcnt, 0, NBUCK * sizeof(int), stream);
    bucket_hist_kernel<<<PBLK, 256, 0, stream>>>(dst, bcnt);
    bucket_scan_kernel<<<1, 256, 0, stream>>>(bcnt, boffs, bcursor);
    partition_kernel<<<PBLK, 256, 0, stream>>>(src, dst, bcursor, pairbuf);
    fill_bucket_kernel<<<NBUCK, 256, 0, stream>>>(pairbuf, boffs, row_ptr, dinv, eidx);

    // ---- conversions ----
    cvt_x_kernel<<<1563, 256, 0, stream>>>(x, ax);
    cvt_w_kernel<<<416, 256, 0, stream>>>(W1_rel, W1_root, W2_rel, W2_root,
                                          Wmu_rel, Wls_rel, Wmu_root, Wls_root,
                                          B1t, B2t, B3t);

    // ---- layer 1 ----
    gather1_kernel<<<1563, 256, 0, stream>>>(row_ptr, eidx, dinv, ax);
    gemm1_mfma<<<dim3(782, 4), 256, 0, stream>>>(ax, B1t, b1, h1);

    // ---- layer 2 ----
    gemm2_mfma<<<dim3(782, 4), 256, 0, stream>>>(h1, B2t, t2, r2);
    gather2_kernel<<<3125, 256, 0, stream>>>(t2, r2, row_ptr, eidx, dinv, b2, h2);

    // ---- mu / logstd ----
    gemm3_mfma<<<dim3(782, 1), 256, 0, stream>>>(h2, B3t, tml, rml);
    gather3_kernel<<<782, 256, 0, stream>>>(tml, rml, row_ptr, eidx, dinv, bmu, bls, out);
}

// Round 6
// 256.011 us; speedup vs baseline: 10.6054x; 1.1252x over previous
//
#include <hip/hip_runtime.h>

#define N_NODES 50000
#define N_EDGES 800000
#define NBUCK 196       // ceil(50000/256) buckets of 256 nodes
#define PBLK 391        // ceil(800000/2048) partition blocks
#define CAP 5120        // bucket window capacity (mean 4082, sigma ~64 -> 16 sigma headroom)

typedef unsigned short ushort_t;
typedef short short8 __attribute__((ext_vector_type(8)));
typedef float floatx4 __attribute__((ext_vector_type(4)));

__device__ __forceinline__ float bf2f(ushort_t u) {
    unsigned v = ((unsigned)u) << 16;
    return __builtin_bit_cast(float, v);
}
__device__ __forceinline__ ushort_t f2bf(float f) {
    unsigned u = __builtin_bit_cast(unsigned, f);
    unsigned r = (u + 0x7FFFu + ((u >> 16) & 1u)) >> 16;  // RNE
    return (ushort_t)r;
}
__device__ __forceinline__ float4 ld4(const float* p) { return *(const float4*)p; }

// ---------------- prep: cvt_x + cvt_w + bucket cursor init (one kernel) ----------------
__global__ __launch_bounds__(256) void prep_kernel(
    const float* __restrict__ x,
    const float* __restrict__ W1_rel, const float* __restrict__ W1_root,
    const float* __restrict__ W2_rel, const float* __restrict__ W2_root,
    const float* __restrict__ Wmu_rel, const float* __restrict__ Wls_rel,
    const float* __restrict__ Wmu_root, const float* __restrict__ Wls_root,
    ushort_t* __restrict__ ax, ushort_t* __restrict__ B1t,
    ushort_t* __restrict__ B2t, ushort_t* __restrict__ B3t,
    int* __restrict__ bcursor) {
    int idx = blockIdx.x * blockDim.x + threadIdx.x;
    if (idx < 400000) {                       // ax[n,64:128] = bf16(x[n,:])
        int n = idx >> 3, c = (idx & 7) * 8;
        float4 v0 = ld4(x + (size_t)n * 64 + c);
        float4 v1 = ld4(x + (size_t)n * 64 + c + 4);
        short8 o;
        o[0] = f2bf(v0.x); o[1] = f2bf(v0.y); o[2] = f2bf(v0.z); o[3] = f2bf(v0.w);
        o[4] = f2bf(v1.x); o[5] = f2bf(v1.y); o[6] = f2bf(v1.z); o[7] = f2bf(v1.w);
        *(short8*)(ax + (size_t)n * 128 + 64 + c) = o;
    } else if (idx < 506496) {                // transposed bf16 weights
        int j = idx - 400000;
        if (j < 32768) {
            int n = j >> 7, k = j & 127;
            float v = (k < 64) ? W1_rel[k * 256 + n] : W1_root[(k - 64) * 256 + n];
            B1t[j] = f2bf(v);
        } else if (j < 98304) {
            int jj = j - 32768;
            int n = jj >> 8, k = jj & 255;
            float v = (n < 128) ? W2_rel[k * 128 + n] : W2_root[k * 128 + (n - 128)];
            B2t[jj] = f2bf(v);
        } else {
            int jj = j - 98304;
            int n = jj >> 7, k = jj & 127;
            const float* W = (n < 16) ? Wmu_rel : (n < 32) ? Wls_rel : (n < 48) ? Wmu_root : Wls_root;
            B3t[jj] = f2bf(W[k * 16 + (n & 15)]);
        }
    } else if (idx < 506496 + NBUCK) {        // bucket window cursors
        int b = idx - 506496;
        bcursor[b] = b * CAP;
    }
}

// ---------------- single-pass partition into fixed bucket windows ----------------
// record = (dstlow<<16)|src  (src<65536, dstlow=dst&255)
__global__ __launch_bounds__(256) void partition_kernel(
    const int* __restrict__ src, const int* __restrict__ dst,
    int* __restrict__ bcursor, unsigned* __restrict__ pairbuf) {
    __shared__ int h[NBUCK];
    __shared__ int cur[NBUCK];
    const int tid = threadIdx.x;
    for (int i = tid; i < NBUCK; i += 256) h[i] = 0;
    __syncthreads();
    const int base = blockIdx.x * 2048;
    int d[8];
    #pragma unroll
    for (int j = 0; j < 8; ++j) {
        int e = base + j * 256 + tid;
        if (e < N_EDGES) { d[j] = dst[e]; atomicAdd(&h[d[j] >> 8], 1); }
        else d[j] = -1;
    }
    __syncthreads();
    for (int i = tid; i < NBUCK; i += 256) {
        int c = h[i];
        cur[i] = c ? atomicAdd(&bcursor[i], c) : 0;
    }
    __syncthreads();
    #pragma unroll
    for (int j = 0; j < 8; ++j) {
        int e = base + j * 256 + tid;
        if (e < N_EDGES) {
            int dd = d[j];
            int slot = atomicAdd(&cur[dd >> 8], 1);
            pairbuf[slot] = (unsigned)src[e] | ((unsigned)(dd & 255) << 16);
        }
    }
}

// per-bucket: node histogram + scan -> row_beg/row_end/dinv; LDS-cursor fill of 16-bit eidx
__global__ __launch_bounds__(256) void fill_bucket_kernel(
    const unsigned* __restrict__ pairbuf, const int* __restrict__ bcursor,
    int* __restrict__ row_beg, int* __restrict__ row_end,
    float* __restrict__ dinv, ushort_t* __restrict__ eidx) {
    __shared__ int h[256];
    __shared__ int sm[256];
    __shared__ int cur[256];
    const int b = blockIdx.x, tid = threadIdx.x;
    const int beg = b * CAP, end = bcursor[b];
    h[tid] = 0;
    __syncthreads();
    for (int i = beg + tid; i < end; i += 256)
        atomicAdd(&h[pairbuf[i] >> 16], 1);
    __syncthreads();
    int c = h[tid];
    sm[tid] = c;
    __syncthreads();
    #pragma unroll
    for (int off = 1; off < 256; off <<= 1) {
        int t = (tid >= off) ? sm[tid - off] : 0;
        __syncthreads();
        sm[tid] += t;
        __syncthreads();
    }
    int exc = beg + sm[tid] - c;
    int node = b * 256 + tid;
    if (node < N_NODES) {
        row_beg[node] = exc;
        row_end[node] = exc + c;
        dinv[node] = c > 0 ? 1.0f / (float)c : 0.0f;
    }
    cur[tid] = exc;
    __syncthreads();
    for (int i = beg + tid; i < end; i += 256) {
        unsigned v = pairbuf[i];
        int slot = atomicAdd(&cur[v >> 16], 1);
        eidx[slot] = (ushort_t)(v & 0xFFFFu);
    }
}

// ---------------- gather 1: ax[:, 0:64] = mean-gather of ax[:, 64:128] ----------------
__global__ __launch_bounds__(256) void gather1_kernel(
    const int* __restrict__ row_beg, const int* __restrict__ row_end,
    const ushort_t* __restrict__ eidx, const float* __restrict__ dinv,
    ushort_t* __restrict__ ax) {
    const int lane = threadIdx.x & 7;
    const int nl = threadIdx.x >> 3;
    const int n = blockIdx.x * 32 + nl;
    if (n >= N_NODES) return;
    const int beg = row_beg[n], end = row_end[n];
    float a0[8] = {}, a1[8] = {}, a2[8] = {}, a3[8] = {};
    int j = beg;
    for (; j + 3 < end; j += 4) {
        int s0 = eidx[j], s1 = eidx[j + 1], s2 = eidx[j + 2], s3 = eidx[j + 3];
        short8 v0 = *(const short8*)(ax + (size_t)s0 * 128 + 64 + lane * 8);
        short8 v1 = *(const short8*)(ax + (size_t)s1 * 128 + 64 + lane * 8);
        short8 v2 = *(const short8*)(ax + (size_t)s2 * 128 + 64 + lane * 8);
        short8 v3 = *(const short8*)(ax + (size_t)s3 * 128 + 64 + lane * 8);
        #pragma unroll
        for (int i = 0; i < 8; ++i) {
            a0[i] += bf2f((ushort_t)v0[i]); a1[i] += bf2f((ushort_t)v1[i]);
            a2[i] += bf2f((ushort_t)v2[i]); a3[i] += bf2f((ushort_t)v3[i]);
        }
    }
    for (; j < end; ++j) {
        int s0 = eidx[j];
        short8 v0 = *(const short8*)(ax + (size_t)s0 * 128 + 64 + lane * 8);
        #pragma unroll
        for (int i = 0; i < 8; ++i) a0[i] += bf2f((ushort_t)v0[i]);
    }
    float d = dinv[n];
    short8 o;
    #pragma unroll
    for (int i = 0; i < 8; ++i) o[i] = f2bf(((a0[i] + a1[i]) + (a2[i] + a3[i])) * d);
    *(short8*)(ax + (size_t)n * 128 + lane * 8) = o;
}

// ---------------- MFMA GEMMs ----------------
// A frag: lane holds A[m=lane&15][k=quad*8+j]; C/D: col=lane&15, row=quad*4+reg.

// gemm1: h1 = relu(ax @ [W1_rel;W1_root] + b1), K=128, N=256
__global__ __launch_bounds__(256) void gemm1_mfma(
    const ushort_t* __restrict__ A, const ushort_t* __restrict__ Bt,
    const float* __restrict__ b1, ushort_t* __restrict__ h1) {
    constexpr int K = 128, KP = K + 8;
    __shared__ ushort_t Bs[64 * KP];
    const int tid = threadIdx.x;
    const int w = tid >> 6, lane = tid & 63;
    const int ln = lane & 15, quad = lane >> 4;
    const int ny = blockIdx.y;
    const int rowbase = blockIdx.x * 64 + w * 16;
    for (int i = tid; i < 64 * K / 8; i += 256) {
        int row = i / (K / 8), off = i % (K / 8);
        *(short8*)(Bs + row * KP + off * 8) = *(const short8*)(Bt + (size_t)(ny * 64 + row) * K + off * 8);
    }
    __syncthreads();
    int r = rowbase + ln; if (r > N_NODES - 1) r = N_NODES - 1;
    short8 a[4];
    #pragma unroll
    for (int s = 0; s < 4; ++s)
        a[s] = *(const short8*)(A + (size_t)r * K + s * 32 + quad * 8);
    floatx4 acc[4] = {};
    #pragma unroll
    for (int f = 0; f < 4; ++f) {
        const ushort_t* bp = Bs + (f * 16 + ln) * KP + quad * 8;
        #pragma unroll
        for (int s = 0; s < 4; ++s) {
            short8 b = *(const short8*)(bp + s * 32);
            acc[f] = __builtin_amdgcn_mfma_f32_16x16x32_bf16(a[s], b, acc[f], 0, 0, 0);
        }
    }
    const int r0 = rowbase + quad * 4;
    #pragma unroll
    for (int f = 0; f < 4; ++f) {
        int n = ny * 64 + f * 16 + ln;
        float bias = b1[n];
        #pragma unroll
        for (int g = 0; g < 4; ++g) {
            int rr = r0 + g;
            if (rr >= N_NODES) continue;
            h1[(size_t)rr * 256 + n] = f2bf(fmaxf(acc[f][g] + bias, 0.0f));
        }
    }
}

// gemm2: [t2 | r2] = h1 @ [W2_rel | W2_root]; t2 bf16 (cols 0-127), r2 fp32 (cols 128-255)
__global__ __launch_bounds__(256) void gemm2_mfma(
    const ushort_t* __restrict__ A, const ushort_t* __restrict__ Bt,
    ushort_t* __restrict__ t2, float* __restrict__ r2) {
    constexpr int K = 256, KP = K + 8;
    __shared__ ushort_t Bs[64 * KP];
    const int tid = threadIdx.x;
    const int w = tid >> 6, lane = tid & 63;
    const int ln = lane & 15, quad = lane >> 4;
    const int ny = blockIdx.y;
    const int rowbase = blockIdx.x * 64 + w * 16;
    for (int i = tid; i < 64 * K / 8; i += 256) {
        int row = i / (K / 8), off = i % (K / 8);
        *(short8*)(Bs + row * KP + off * 8) = *(const short8*)(Bt + (size_t)(ny * 64 + row) * K + off * 8);
    }
    __syncthreads();
    int r = rowbase + ln; if (r > N_NODES - 1) r = N_NODES - 1;
    short8 a[8];
    #pragma unroll
    for (int s = 0; s < 8; ++s)
        a[s] = *(const short8*)(A + (size_t)r * K + s * 32 + quad * 8);
    floatx4 acc[4] = {};
    #pragma unroll
    for (int f = 0; f < 4; ++f) {
        const ushort_t* bp = Bs + (f * 16 + ln) * KP + quad * 8;
        #pragma unroll
        for (int s = 0; s < 8; ++s) {
            short8 b = *(const short8*)(bp + s * 32);
            acc[f] = __builtin_amdgcn_mfma_f32_16x16x32_bf16(a[s], b, acc[f], 0, 0, 0);
        }
    }
    const int r0 = rowbase + quad * 4;
    #pragma unroll
    for (int f = 0; f < 4; ++f) {
        int n = ny * 64 + f * 16 + ln;
        #pragma unroll
        for (int g = 0; g < 4; ++g) {
            int rr = r0 + g;
            if (rr >= N_NODES) continue;
            float v = acc[f][g];
            if (n < 128) t2[(size_t)rr * 128 + n] = f2bf(v);
            else r2[(size_t)rr * 128 + (n - 128)] = v;
        }
    }
}

// ---------------- fused gather2 + combine + gemm3 ----------------
// Per block: 64 nodes. Phase 1: h2 row = relu(mean-gather(t2) + r2 + b2) -> LDS As (bf16).
// Phase 2: [tml | rml] = As @ B3t via MFMA.
__global__ __launch_bounds__(256) void g2g3_kernel(
    const ushort_t* __restrict__ t2, const float* __restrict__ r2,
    const int* __restrict__ row_beg, const int* __restrict__ row_end,
    const ushort_t* __restrict__ eidx, const float* __restrict__ dinv,
    const float* __restrict__ b2, const ushort_t* __restrict__ B3t,
    ushort_t* __restrict__ tml, float* __restrict__ rml) {
    constexpr int K = 128, KP = K + 8;
    __shared__ ushort_t As[64 * KP];
    __shared__ ushort_t Bs[64 * KP];
    const int tid = threadIdx.x;
    const int nb = blockIdx.x * 64;
    // stage B3t (64x128) -> Bs
    for (int i = tid; i < 64 * 16; i += 256) {
        int row = i >> 4, off = (i & 15) * 8;
        *(short8*)(Bs + row * KP + off) = *(const short8*)(B3t + row * 128 + off);
    }
    // phase 1: 4 threads/node, 32 ch each
    const int nl = tid >> 2, lane = tid & 3;
    const int n = nb + nl;
    if (n < N_NODES) {
        const int beg = row_beg[n], end = row_end[n];
        float acc[32];
        #pragma unroll
        for (int i = 0; i < 32; ++i) acc[i] = 0.0f;
        for (int j = beg; j < end; ++j) {
            const ushort_t* tp = t2 + (size_t)eidx[j] * 128 + lane * 32;
            short8 v0 = *(const short8*)(tp);
            short8 v1 = *(const short8*)(tp + 8);
            short8 v2 = *(const short8*)(tp + 16);
            short8 v3 = *(const short8*)(tp + 24);
            #pragma unroll
            for (int i = 0; i < 8; ++i) {
                acc[i]      += bf2f((ushort_t)v0[i]);
                acc[8 + i]  += bf2f((ushort_t)v1[i]);
                acc[16 + i] += bf2f((ushort_t)v2[i]);
                acc[24 + i] += bf2f((ushort_t)v3[i]);
            }
        }
        float d = dinv[n];
        const float* rp = r2 + (size_t)n * 128 + lane * 32;
        const float* bp = b2 + lane * 32;
        ushort_t* ap = As + nl * KP + lane * 32;
        #pragma unroll
        for (int q = 0; q < 4; ++q) {
            float4 ra = ld4(rp + q * 8), rb = ld4(rp + q * 8 + 4);
            float4 ba = ld4(bp + q * 8), bb = ld4(bp + q * 8 + 4);
            float rr[8] = {ra.x, ra.y, ra.z, ra.w, rb.x, rb.y, rb.z, rb.w};
            float bc[8] = {ba.x, ba.y, ba.z, ba.w, bb.x, bb.y, bb.z, bb.w};
            short8 o;
            #pragma unroll
            for (int i = 0; i < 8; ++i)
                o[i] = f2bf(fmaxf(acc[q * 8 + i] * d + rr[i] + bc[i], 0.0f));
            *(short8*)(ap + q * 8) = o;
        }
    }
    __syncthreads();
    // phase 2: MFMA, M=64 (this block's nodes), N=64, K=128
    const int w = tid >> 6, lane64 = tid & 63;
    const int ln = lane64 & 15, quad = lane64 >> 4;
    short8 a[4];
    #pragma unroll
    for (int s = 0; s < 4; ++s)
        a[s] = *(const short8*)(As + (w * 16 + ln) * KP + s * 32 + quad * 8);
    floatx4 accv[4] = {};
    #pragma unroll
    for (int f = 0; f < 4; ++f) {
        const ushort_t* bpp = Bs + (f * 16 + ln) * KP + quad * 8;
        #pragma unroll
        for (int s = 0; s < 4; ++s) {
            short8 b = *(const short8*)(bpp + s * 32);
            accv[f] = __builtin_amdgcn_mfma_f32_16x16x32_bf16(a[s], b, accv[f], 0, 0, 0);
        }
    }
    const int r0 = nb + w * 16 + quad * 4;
    #pragma unroll
    for (int f = 0; f < 4; ++f) {
        int ncol = f * 16 + ln;
        #pragma unroll
        for (int g = 0; g < 4; ++g) {
            int rr = r0 + g;
            if (rr >= N_NODES) continue;
            float v = accv[f][g];
            if (ncol < 32) tml[(size_t)rr * 32 + ncol] = f2bf(v);
            else rml[(size_t)rr * 32 + (ncol - 32)] = v;
        }
    }
}

// ---------------- gather 3 (fused combine + split write) ----------------
__global__ __launch_bounds__(256) void gather3_kernel(
    const ushort_t* __restrict__ tml, const float* __restrict__ rml,
    const int* __restrict__ row_beg, const int* __restrict__ row_end,
    const ushort_t* __restrict__ eidx, const float* __restrict__ dinv,
    const float* __restrict__ bmu, const float* __restrict__ bls,
    float* __restrict__ out) {
    const int lane = threadIdx.x & 3;
    const int nl = threadIdx.x >> 2;
    const int n = blockIdx.x * 64 + nl;
    if (n >= N_NODES) return;
    const int beg = row_beg[n], end = row_end[n];
    float a0[8] = {}, a1[8] = {};
    int j = beg;
    for (; j + 1 < end; j += 2) {
        int s0 = eidx[j], s1 = eidx[j + 1];
        short8 v0 = *(const short8*)(tml + (size_t)s0 * 32 + lane * 8);
        short8 v1 = *(const short8*)(tml + (size_t)s1 * 32 + lane * 8);
        #pragma unroll
        for (int i = 0; i < 8; ++i) { a0[i] += bf2f((ushort_t)v0[i]); a1[i] += bf2f((ushort_t)v1[i]); }
    }
    if (j < end) {
        int s0 = eidx[j];
        short8 v0 = *(const short8*)(tml + (size_t)s0 * 32 + lane * 8);
        #pragma unroll
        for (int i = 0; i < 8; ++i) a0[i] += bf2f((ushort_t)v0[i]);
    }
    float d = dinv[n];
    const float* bias = (lane < 2) ? (bmu + lane * 8) : (bls + (lane - 2) * 8);
    float4 ra = ld4(rml + (size_t)n * 32 + lane * 8);
    float4 rb = ld4(rml + (size_t)n * 32 + lane * 8 + 4);
    float4 ba = ld4(bias);
    float4 bb = ld4(bias + 4);
    float rr[8] = {ra.x, ra.y, ra.z, ra.w, rb.x, rb.y, rb.z, rb.w};
    float bc[8] = {ba.x, ba.y, ba.z, ba.w, bb.x, bb.y, bb.z, bb.w};
    float res[8];
    #pragma unroll
    for (int i = 0; i < 8; ++i) res[i] = (a0[i] + a1[i]) * d + rr[i] + bc[i];
    float* base = (lane < 2) ? (out + (size_t)n * 16 + lane * 8)
                             : (out + 800000u + (size_t)n * 16 + (lane - 2) * 8);
    *(float4*)(base) = make_float4(res[0], res[1], res[2], res[3]);
    *(float4*)(base + 4) = make_float4(res[4], res[5], res[6], res[7]);
}

extern "C" void kernel_launch(void* const* d_in, const int* in_sizes, int n_in,
                              void* d_out, int out_size, void* d_ws, size_t ws_size,
                              hipStream_t stream) {
    const float* x       = (const float*)d_in[0];
    const float* W1_rel  = (const float*)d_in[1];
    const float* b1      = (const float*)d_in[2];
    const float* W1_root = (const float*)d_in[3];
    const float* W2_rel  = (const float*)d_in[4];
    const float* b2      = (const float*)d_in[5];
    const float* W2_root = (const float*)d_in[6];
    const float* Wmu_rel = (const float*)d_in[7];
    const float* bmu     = (const float*)d_in[8];
    const float* Wmu_root= (const float*)d_in[9];
    const float* Wls_rel = (const float*)d_in[10];
    const float* bls     = (const float*)d_in[11];
    const float* Wls_root= (const float*)d_in[12];
    const int*   ei      = (const int*)d_in[13];
    const int* src = ei;
    const int* dst = ei + N_EDGES;

    // ---- workspace layout ----
    int*      bcursor = (int*)d_ws;                      //       256
    int*      row_beg = bcursor + 256;                   //    50,048
    int*      row_end = row_beg + 50048;                 //    50,048
    unsigned* pairbuf = (unsigned*)(row_end + 50048);    // 1,003,520 (196*5120)
    ushort_t* eidx    = (ushort_t*)(pairbuf + 1003520);  // 1,003,520 ush = 501,760 ints
    float*    dinv    = (float*)(eidx + 1003520);        //    50,000
    ushort_t* ub      = (ushort_t*)(dinv + 50000);
    ushort_t* ax   = ub;                       //  6,400,000  [N,128] bf16: [agg | x]
    ushort_t* h1   = ax + 6400000;             // 12,800,000  [N,256]
    ushort_t* t2   = h1 + 12800000;            //  6,400,000  [N,128]
    ushort_t* tml  = t2 + 6400000;             //  1,600,000  [N,32]
    ushort_t* B1t  = tml + 1600000;            //     32,768
    ushort_t* B2t  = B1t + 32768;              //     65,536
    ushort_t* B3t  = B2t + 65536;              //      8,192
    float* r2      = (float*)(B3t + 8192);     //  6,400,000  [N,128] f32
    float* rml     = r2 + 6400000;             //  1,600,000  [N,32]  f32
    float* out     = (float*)d_out;

    // ---- prep (x/W conversions + bucket cursors) ----
    prep_kernel<<<1980, 256, 0, stream>>>(x, W1_rel, W1_root, W2_rel, W2_root,
                                          Wmu_rel, Wls_rel, Wmu_root, Wls_root,
                                          ax, B1t, B2t, B3t, bcursor);

    // ---- CSR build (single-pass counting sort into fixed windows) ----
    partition_kernel<<<PBLK, 256, 0, stream>>>(src, dst, bcursor, pairbuf);
    fill_bucket_kernel<<<NBUCK, 256, 0, stream>>>(pairbuf, bcursor, row_beg, row_end, dinv, eidx);

    // ---- layer 1 ----
    gather1_kernel<<<1563, 256, 0, stream>>>(row_beg, row_end, eidx, dinv, ax);
    gemm1_mfma<<<dim3(782, 4), 256, 0, stream>>>(ax, B1t, b1, h1);

    // ---- layer 2 + layer-3 transform (fused) ----
    gemm2_mfma<<<dim3(782, 4), 256, 0, stream>>>(h1, B2t, t2, r2);
    g2g3_kernel<<<782, 256, 0, stream>>>(t2, r2, row_beg, row_end, eidx, dinv, b2, B3t, tml, rml);

    // ---- mu / logstd final aggregation ----
    gather3_kernel<<<782, 256, 0, stream>>>(tml, rml, row_beg, row_end, eidx, dinv, bmu, bls, out);
}